// Round 1
// baseline (581.478 us; speedup 1.0000x reference)
//
#include <hip/hip_runtime.h>
#include <math.h>

#define NNODES 100000
#define NEDGES 1600000

// ---------------- graph prep ----------------

__global__ __launch_bounds__(256) void count_kernel(const int* __restrict__ dst,
                                                    int* __restrict__ cnt, int E) {
    int i = blockIdx.x * 256 + threadIdx.x;
    if (i < E) atomicAdd(&cnt[dst[i]], 1);
}

__global__ __launch_bounds__(256) void dinv_kernel(const int* __restrict__ cnt,
                                                   float* __restrict__ dinv, int n) {
    int i = blockIdx.x * 256 + threadIdx.x;
    if (i < n) dinv[i] = rsqrtf((float)cnt[i] + 1.0f);
}

// per-block exclusive scan over 1024 elements (256 thr x 4)
__global__ __launch_bounds__(256) void scan1_kernel(const int* __restrict__ cnt,
                                                    int* __restrict__ off,
                                                    int* __restrict__ bsum, int n) {
    __shared__ int tmp[256];
    int tid = threadIdx.x;
    int t4 = blockIdx.x * 1024 + tid * 4;
    int v0 = (t4 + 0 < n) ? cnt[t4 + 0] : 0;
    int v1 = (t4 + 1 < n) ? cnt[t4 + 1] : 0;
    int v2 = (t4 + 2 < n) ? cnt[t4 + 2] : 0;
    int v3 = (t4 + 3 < n) ? cnt[t4 + 3] : 0;
    int ssum = v0 + v1 + v2 + v3;
    tmp[tid] = ssum;
    __syncthreads();
    for (int d = 1; d < 256; d <<= 1) {
        int x = (tid >= d) ? tmp[tid - d] : 0;
        __syncthreads();
        tmp[tid] += x;
        __syncthreads();
    }
    int run = tmp[tid] - ssum;  // exclusive prefix of this thread
    if (t4 + 0 < n) off[t4 + 0] = run; run += v0;
    if (t4 + 1 < n) off[t4 + 1] = run; run += v1;
    if (t4 + 2 < n) off[t4 + 2] = run; run += v2;
    if (t4 + 3 < n) off[t4 + 3] = run;
    if (tid == 255) bsum[blockIdx.x] = tmp[255];
}

__global__ __launch_bounds__(256) void scan2_kernel(const int* __restrict__ bsum,
                                                    int* __restrict__ bsum_ex, int nb) {
    __shared__ int tmp[256];
    int tid = threadIdx.x;
    int v = (tid < nb) ? bsum[tid] : 0;
    tmp[tid] = v;
    __syncthreads();
    for (int d = 1; d < 256; d <<= 1) {
        int x = (tid >= d) ? tmp[tid - d] : 0;
        __syncthreads();
        tmp[tid] += x;
        __syncthreads();
    }
    bsum_ex[tid] = tmp[tid] - v;  // exclusive
}

__global__ __launch_bounds__(256) void scan3_kernel(int* __restrict__ off,
                                                    const int* __restrict__ bsum_ex, int n) {
    int i = blockIdx.x * 256 + threadIdx.x;
    if (i < n) off[i] += bsum_ex[i >> 10];
}

__global__ __launch_bounds__(256) void scatter_kernel(const int* __restrict__ src,
                                                      const int* __restrict__ dst,
                                                      const int* __restrict__ off,
                                                      int* __restrict__ cur,
                                                      int* __restrict__ csr, int E) {
    int i = blockIdx.x * 256 + threadIdx.x;
    if (i < E) {
        int d = dst[i];
        int p = off[d] + atomicAdd(&cur[d], 1);
        csr[p] = src[i];
    }
}

// ---------------- W34 = W3 @ W4, b34 = b3 @ W4 + b4 ----------------

__global__ __launch_bounds__(64) void w34_kernel(const float* __restrict__ W3,
                                                 const float* __restrict__ W4,
                                                 const float* __restrict__ b3,
                                                 const float* __restrict__ b4,
                                                 float* __restrict__ W34,
                                                 float* __restrict__ b34) {
    int j = threadIdx.x;
    int i = blockIdx.x;
    if (i < 64) {
        float a = 0.f;
        for (int k = 0; k < 256; ++k) a = fmaf(W3[i * 256 + k], W4[k * 64 + j], a);
        W34[i * 64 + j] = a;
    } else {
        float a = b4[j];
        for (int k = 0; k < 256; ++k) a = fmaf(b3[k], W4[k * 64 + j], a);
        b34[j] = a;
    }
}

// ---------------- GEMM: out[N,64] = in[N,CIN] @ W[CIN,64] (+bias, relu) ----------------

template <int CIN, bool BIAS, bool RELU>
__global__ __launch_bounds__(256) void gemm64_kernel(const float* __restrict__ in,
                                                     const float* __restrict__ W,
                                                     const float* __restrict__ bias,
                                                     float* __restrict__ out, int n) {
    __shared__ float sW[CIN][68];
    __shared__ float sX[64][68];
    int tid = threadIdx.x;
    // stage W (row-major [CIN][64])
    for (int i = tid; i < CIN * 64; i += 256) sW[i >> 6][i & 63] = W[i];

    int base = blockIdx.x * 64;
    int cg = tid & 15, ng = tid >> 4;
    int c0 = cg * 4, n0 = ng * 4;
    float acc[4][4] = {};

    for (int kc = 0; kc < CIN; kc += 64) {
        __syncthreads();
        // stage 64 nodes x 64 k, transposed: sX[k][node]
        for (int i = tid; i < 64 * 64; i += 256) {
            int nl = i >> 6, kl = i & 63;
            int node = base + nl;
            float v = 0.f;
            if (node < n) v = in[node * CIN + kc + kl];
            sX[kl][nl] = v;
        }
        __syncthreads();
#pragma unroll 16
        for (int k = 0; k < 64; ++k) {
            const float4 wv = *(const float4*)(&sW[kc + k][c0]);
            const float4 xv = *(const float4*)(&sX[k][n0]);
            float wa[4] = {wv.x, wv.y, wv.z, wv.w};
            float xa[4] = {xv.x, xv.y, xv.z, xv.w};
#pragma unroll
            for (int i2 = 0; i2 < 4; ++i2)
#pragma unroll
                for (int j2 = 0; j2 < 4; ++j2) acc[i2][j2] = fmaf(xa[i2], wa[j2], acc[i2][j2]);
        }
    }

    float4 bv = make_float4(0.f, 0.f, 0.f, 0.f);
    if (BIAS) bv = *(const float4*)(&bias[c0]);
#pragma unroll
    for (int i2 = 0; i2 < 4; ++i2) {
        int node = base + n0 + i2;
        if (node < n) {
            float4 ov;
            ov.x = acc[i2][0] + bv.x;
            ov.y = acc[i2][1] + bv.y;
            ov.z = acc[i2][2] + bv.z;
            ov.w = acc[i2][3] + bv.w;
            if (RELU) {
                ov.x = fmaxf(ov.x, 0.f); ov.y = fmaxf(ov.y, 0.f);
                ov.z = fmaxf(ov.z, 0.f); ov.w = fmaxf(ov.w, 0.f);
            }
            *(float4*)(&out[node * 64 + c0]) = ov;
        }
    }
}

// ---------------- aggregation: one wave per dst node, 64 lanes = 64 ch ----------------

__global__ __launch_bounds__(256) void aggregate_kernel(const float* __restrict__ h,
                                                        const int* __restrict__ csr,
                                                        const int* __restrict__ off,
                                                        const int* __restrict__ cnt,
                                                        const float* __restrict__ dinv,
                                                        const float* __restrict__ bias,
                                                        float* __restrict__ out, int n) {
    int wid = (blockIdx.x * 256 + threadIdx.x) >> 6;
    int lane = threadIdx.x & 63;
    if (wid >= n) return;
    float di = dinv[wid];
    float acc = h[wid * 64 + lane] * di * di;  // self-loop
    int s = off[wid];
    int e = s + cnt[wid];
    int i = s;
    for (; i + 4 <= e; i += 4) {
        int s0 = csr[i], s1 = csr[i + 1], s2 = csr[i + 2], s3 = csr[i + 3];
        float w0 = dinv[s0] * di, w1 = dinv[s1] * di, w2 = dinv[s2] * di, w3 = dinv[s3] * di;
        float h0 = h[s0 * 64 + lane], h1 = h[s1 * 64 + lane];
        float h2 = h[s2 * 64 + lane], h3 = h[s3 * 64 + lane];
        acc = fmaf(h0, w0, acc);
        acc = fmaf(h1, w1, acc);
        acc = fmaf(h2, w2, acc);
        acc = fmaf(h3, w3, acc);
    }
    for (; i < e; ++i) {
        int ss = csr[i];
        acc = fmaf(h[ss * 64 + lane], dinv[ss] * di, acc);
    }
    acc += bias[lane];
    acc = fmaxf(acc, 0.f);
    out[wid * 64 + lane] = acc;
}

// ---------------- log_softmax over 64 channels: one wave per node ----------------

__global__ __launch_bounds__(256) void logsoftmax_kernel(const float* __restrict__ in,
                                                         float* __restrict__ out, int n) {
    int wid = (blockIdx.x * 256 + threadIdx.x) >> 6;
    int lane = threadIdx.x & 63;
    if (wid >= n) return;
    float v = in[wid * 64 + lane];
    float m = v;
    for (int d = 32; d >= 1; d >>= 1) m = fmaxf(m, __shfl_xor(m, d));
    float ev = __expf(v - m);
    float ssum = ev;
    for (int d = 32; d >= 1; d >>= 1) ssum += __shfl_xor(ssum, d);
    out[wid * 64 + lane] = v - m - __logf(ssum);
}

// ---------------- launch ----------------

extern "C" void kernel_launch(void* const* d_in, const int* in_sizes, int n_in,
                              void* d_out, int out_size, void* d_ws, size_t ws_size,
                              hipStream_t stream) {
    const float* x  = (const float*)d_in[0];
    const int*   ei = (const int*)d_in[1];   // int32 (JAX x64 disabled demotes int64)
    const float* W1 = (const float*)d_in[2];
    const float* b1 = (const float*)d_in[3];
    const float* W2 = (const float*)d_in[4];
    const float* b2 = (const float*)d_in[5];
    const float* W3 = (const float*)d_in[6];
    const float* b3 = (const float*)d_in[7];
    const float* W4 = (const float*)d_in[8];
    const float* b4 = (const float*)d_in[9];
    float* outp = (float*)d_out;

    const int N = NNODES;
    const int E = NEDGES;
    const int* srcp = ei;
    const int* dstp = ei + E;

    // workspace layout
    char* w = (char*)d_ws;
    size_t o = 0;
    auto alloc = [&](size_t bytes) { size_t r = o; o = (o + bytes + 255) & ~(size_t)255; return r; };
    size_t cnt_off  = alloc((size_t)N * 4);
    size_t cur_off  = alloc((size_t)N * 4);
    size_t off_off  = alloc((size_t)N * 4);
    size_t bs_off   = alloc(256 * 4);
    size_t bse_off  = alloc(256 * 4);
    size_t dinv_off = alloc((size_t)N * 4);
    size_t csr_off  = alloc((size_t)E * 4);
    size_t A_off    = alloc((size_t)N * 64 * 4);
    size_t B_off    = alloc((size_t)N * 64 * 4);
    size_t w34_off  = alloc(64 * 64 * 4);
    size_t b34_off  = alloc(64 * 4);

    int*   cnt  = (int*)(w + cnt_off);
    int*   cur  = (int*)(w + cur_off);
    int*   off  = (int*)(w + off_off);
    int*   bs   = (int*)(w + bs_off);
    int*   bse  = (int*)(w + bse_off);
    float* dinv = (float*)(w + dinv_off);
    int*   csr  = (int*)(w + csr_off);
    float* bufA = (float*)(w + A_off);
    float* bufB = (float*)(w + B_off);
    float* W34  = (float*)(w + w34_off);
    float* b34  = (float*)(w + b34_off);

    // zero cnt + cur (contiguous span)
    hipMemsetAsync(w + cnt_off, 0, cur_off + (size_t)N * 4 - cnt_off, stream);

    const int eb = (E + 255) / 256;     // 6250
    const int nb = (N + 255) / 256;     // 391
    const int sb = (N + 1023) / 1024;   // 98

    count_kernel<<<eb, 256, 0, stream>>>(dstp, cnt, E);
    dinv_kernel<<<nb, 256, 0, stream>>>(cnt, dinv, N);
    scan1_kernel<<<sb, 256, 0, stream>>>(cnt, off, bs, N);
    scan2_kernel<<<1, 256, 0, stream>>>(bs, bse, sb);
    scan3_kernel<<<nb, 256, 0, stream>>>(off, bse, N);
    scatter_kernel<<<eb, 256, 0, stream>>>(srcp, dstp, off, cur, csr, E);

    w34_kernel<<<65, 64, 0, stream>>>(W3, W4, b3, b4, W34, b34);

    const int gb = (N + 63) / 64;       // 1563
    const int ab = (N + 3) / 4;         // 25000 (4 waves/block)

    // layer 1: lin -> aggregate(+b1,relu)
    gemm64_kernel<128, false, false><<<gb, 256, 0, stream>>>(x, W1, nullptr, bufA, N);
    aggregate_kernel<<<ab, 256, 0, stream>>>(bufA, csr, off, cnt, dinv, b1, bufB, N);
    // layer 2
    gemm64_kernel<64, false, false><<<gb, 256, 0, stream>>>(bufB, W2, nullptr, bufA, N);
    aggregate_kernel<<<ab, 256, 0, stream>>>(bufA, csr, off, cnt, dinv, b2, bufB, N);
    // fused layers 3+4 (linear-linear collapsed), then log_softmax
    gemm64_kernel<64, true, false><<<gb, 256, 0, stream>>>(bufB, W34, b34, bufA, N);
    logsoftmax_kernel<<<ab, 256, 0, stream>>>(bufA, outp, N);
}

// Round 2
// 405.773 us; speedup vs baseline: 1.4330x; 1.4330x over previous
//
#include <hip/hip_runtime.h>
#include <hip/hip_bf16.h>
#include <math.h>

#define NNODES 100000
#define NEDGES 1600000

typedef __bf16 bf16x8 __attribute__((ext_vector_type(8)));
typedef float f32x4 __attribute__((ext_vector_type(4)));

static __device__ inline unsigned short f2bf(float f) {
    __hip_bfloat16 h = __float2bfloat16(f);
    return *reinterpret_cast<unsigned short*>(&h);
}

// ---------------- graph prep ----------------

// count + rank in one pass: rank[i] = slot of edge i within its dst bucket
__global__ __launch_bounds__(256) void count_kernel(const int* __restrict__ dst,
                                                    int* __restrict__ cnt,
                                                    unsigned short* __restrict__ rank, int E) {
    int i = blockIdx.x * 256 + threadIdx.x;
    if (i < E) {
        int r = atomicAdd(&cnt[dst[i]], 1);
        rank[i] = (unsigned short)r;
    }
}

__global__ __launch_bounds__(256) void dinv_kernel(const int* __restrict__ cnt,
                                                   float* __restrict__ dinv, int n) {
    int i = blockIdx.x * 256 + threadIdx.x;
    if (i < n) dinv[i] = rsqrtf((float)cnt[i] + 1.0f);
}

// per-block exclusive scan over 1024 elements (256 thr x 4)
__global__ __launch_bounds__(256) void scan1_kernel(const int* __restrict__ cnt,
                                                    int* __restrict__ off,
                                                    int* __restrict__ bsum, int n) {
    __shared__ int tmp[256];
    int tid = threadIdx.x;
    int t4 = blockIdx.x * 1024 + tid * 4;
    int v0 = (t4 + 0 < n) ? cnt[t4 + 0] : 0;
    int v1 = (t4 + 1 < n) ? cnt[t4 + 1] : 0;
    int v2 = (t4 + 2 < n) ? cnt[t4 + 2] : 0;
    int v3 = (t4 + 3 < n) ? cnt[t4 + 3] : 0;
    int ssum = v0 + v1 + v2 + v3;
    tmp[tid] = ssum;
    __syncthreads();
    for (int d = 1; d < 256; d <<= 1) {
        int x = (tid >= d) ? tmp[tid - d] : 0;
        __syncthreads();
        tmp[tid] += x;
        __syncthreads();
    }
    int run = tmp[tid] - ssum;  // exclusive prefix of this thread
    if (t4 + 0 < n) off[t4 + 0] = run; run += v0;
    if (t4 + 1 < n) off[t4 + 1] = run; run += v1;
    if (t4 + 2 < n) off[t4 + 2] = run; run += v2;
    if (t4 + 3 < n) off[t4 + 3] = run;
    if (tid == 255) bsum[blockIdx.x] = tmp[255];
}

__global__ __launch_bounds__(256) void scan2_kernel(const int* __restrict__ bsum,
                                                    int* __restrict__ bsum_ex, int nb) {
    __shared__ int tmp[256];
    int tid = threadIdx.x;
    int v = (tid < nb) ? bsum[tid] : 0;
    tmp[tid] = v;
    __syncthreads();
    for (int d = 1; d < 256; d <<= 1) {
        int x = (tid >= d) ? tmp[tid - d] : 0;
        __syncthreads();
        tmp[tid] += x;
        __syncthreads();
    }
    bsum_ex[tid] = tmp[tid] - v;  // exclusive
}

__global__ __launch_bounds__(256) void scan3_kernel(int* __restrict__ off,
                                                    const int* __restrict__ bsum_ex, int n) {
    int i = blockIdx.x * 256 + threadIdx.x;
    if (i < n) off[i] += bsum_ex[i >> 10];
}

// atomic-free scatter: position = off[dst] + precomputed rank
__global__ __launch_bounds__(256) void scatter_kernel(const int* __restrict__ src,
                                                      const int* __restrict__ dst,
                                                      const int* __restrict__ off,
                                                      const unsigned short* __restrict__ rank,
                                                      int* __restrict__ csr, int E) {
    int i = blockIdx.x * 256 + threadIdx.x;
    if (i < E) {
        int d = dst[i];
        csr[off[d] + (int)rank[i]] = src[i];
    }
}

// ---------------- W34 = W3 @ W4 (fp32), b34 = b3 @ W4 + b4 ----------------

__global__ __launch_bounds__(64) void w34_kernel(const float* __restrict__ W3,
                                                 const float* __restrict__ W4,
                                                 const float* __restrict__ b3,
                                                 const float* __restrict__ b4,
                                                 float* __restrict__ W34,
                                                 float* __restrict__ b34) {
    int j = threadIdx.x;
    int i = blockIdx.x;
    if (i < 64) {
        float a = 0.f;
        for (int k = 0; k < 256; ++k) a = fmaf(W3[i * 256 + k], W4[k * 64 + j], a);
        W34[i * 64 + j] = a;
    } else {
        float a = b4[j];
        for (int k = 0; k < 256; ++k) a = fmaf(b3[k], W4[k * 64 + j], a);
        b34[j] = a;
    }
}

// ---------------- pack W[K][64] fp32 -> bf16 B-fragment layout ----------------
// Wp[((t*S + s)*64 + lane)*8 + i] = W[k][ch], k = s*32 + (lane>>4)*8 + i, ch = t*16 + (lane&15)

template <int K>
__global__ __launch_bounds__(256) void packW_kernel(const float* __restrict__ W,
                                                    unsigned short* __restrict__ Wp) {
    constexpr int S = K / 32;
    int idx = blockIdx.x * 256 + threadIdx.x;
    if (idx >= 64 * K) return;
    int i = idx & 7;
    int rest = idx >> 3;
    int lane = rest & 63; rest >>= 6;
    int s = rest % S;
    int t = rest / S;
    int q = lane >> 4, lo = lane & 15;
    int k = s * 32 + q * 8 + i;
    int ch = t * 16 + lo;
    Wp[idx] = f2bf(W[k * 64 + ch]);
}

// ---------------- x fp32 -> bf16 ----------------

__global__ __launch_bounds__(256) void tobf16_kernel(const float* __restrict__ in,
                                                     unsigned short* __restrict__ outp, int nElem) {
    int i = blockIdx.x * 256 + threadIdx.x;
    int idx = i * 4;
    if (idx + 3 < nElem) {
        float4 v = *(const float4*)(in + idx);
        ushort4 o;
        o.x = f2bf(v.x); o.y = f2bf(v.y); o.z = f2bf(v.z); o.w = f2bf(v.w);
        *(ushort4*)(outp + idx) = o;
    }
}

// ---------------- MFMA GEMM: out[N,64] = Xbf[N,K] @ W[K,64] ----------------
// block = 256 thr = 4 waves; wave handles 16 nodes x 64 ch via 4 C-tiles of 16x16.
// A frag: lane holds X[node = base + (lane&15)][k = (lane>>4)*8 + j], j=0..7
// B frag from pre-packed Wp (lane-contiguous 16B loads, L1-resident)
// D: node = base + (lane>>4)*4 + reg, ch = t*16 + (lane&15)

template <int K, bool LSM>
__global__ __launch_bounds__(256) void gemm_mfma_kernel(const unsigned short* __restrict__ Xb,
                                                        const unsigned short* __restrict__ Wp,
                                                        const float* __restrict__ bias,
                                                        float* __restrict__ out, int n) {
    constexpr int S = K / 32;
    int w = threadIdx.x >> 6, lane = threadIdx.x & 63;
    int q = lane >> 4, lo = lane & 15;
    int base = blockIdx.x * 64 + w * 16;
    int nodeA = base + lo;
    int na = nodeA < n ? nodeA : 0;
    const unsigned short* xrow = Xb + (size_t)na * K + q * 8;

    f32x4 acc[4] = {};
#pragma unroll
    for (int s = 0; s < S; ++s) {
        bf16x8 a = *(const bf16x8*)(xrow + s * 32);
#pragma unroll
        for (int t = 0; t < 4; ++t) {
            bf16x8 b = *(const bf16x8*)(Wp + ((size_t)(t * S + s) * 64 + lane) * 8);
            acc[t] = __builtin_amdgcn_mfma_f32_16x16x32_bf16(a, b, acc[t], 0, 0, 0);
        }
    }

    if (!LSM) {
#pragma unroll
        for (int t = 0; t < 4; ++t)
#pragma unroll
            for (int r = 0; r < 4; ++r) {
                int node = base + q * 4 + r;
                if (node < n) out[(size_t)node * 64 + t * 16 + lo] = acc[t][r];
            }
    } else {
        // fused bias + log_softmax over 64 channels
#pragma unroll
        for (int r = 0; r < 4; ++r) {
            int node = base + q * 4 + r;
            float v0 = acc[0][r] + bias[0 * 16 + lo];
            float v1 = acc[1][r] + bias[1 * 16 + lo];
            float v2 = acc[2][r] + bias[2 * 16 + lo];
            float v3 = acc[3][r] + bias[3 * 16 + lo];
            float mx = fmaxf(fmaxf(v0, v1), fmaxf(v2, v3));
            for (int d = 1; d < 16; d <<= 1) mx = fmaxf(mx, __shfl_xor(mx, d));
            float sm = __expf(v0 - mx) + __expf(v1 - mx) + __expf(v2 - mx) + __expf(v3 - mx);
            for (int d = 1; d < 16; d <<= 1) sm += __shfl_xor(sm, d);
            float lse = mx + __logf(sm);
            if (node < n) {
                out[(size_t)node * 64 + 0 * 16 + lo] = v0 - lse;
                out[(size_t)node * 64 + 1 * 16 + lo] = v1 - lse;
                out[(size_t)node * 64 + 2 * 16 + lo] = v2 - lse;
                out[(size_t)node * 64 + 3 * 16 + lo] = v3 - lse;
            }
        }
    }
}

// ---------------- aggregation: one wave per dst node, 64 lanes = 64 ch ----------------
// reads fp32 h rows, writes bf16 (next GEMM's A operand). bias+relu fused.

__global__ __launch_bounds__(256) void aggregate_kernel(const float* __restrict__ h,
                                                        const int* __restrict__ csr,
                                                        const int* __restrict__ off,
                                                        const int* __restrict__ cnt,
                                                        const float* __restrict__ dinv,
                                                        const float* __restrict__ bias,
                                                        unsigned short* __restrict__ out, int n) {
    int wid = (blockIdx.x * 256 + threadIdx.x) >> 6;
    int lane = threadIdx.x & 63;
    if (wid >= n) return;
    float di = dinv[wid];
    float acc = h[(size_t)wid * 64 + lane] * di * di;  // self-loop
    int s = off[wid];
    int e = s + cnt[wid];
    int i = s;
    for (; i + 4 <= e; i += 4) {
        int s0 = csr[i], s1 = csr[i + 1], s2 = csr[i + 2], s3 = csr[i + 3];
        float w0 = dinv[s0] * di, w1 = dinv[s1] * di, w2 = dinv[s2] * di, w3 = dinv[s3] * di;
        float h0 = h[(size_t)s0 * 64 + lane], h1 = h[(size_t)s1 * 64 + lane];
        float h2 = h[(size_t)s2 * 64 + lane], h3 = h[(size_t)s3 * 64 + lane];
        acc = fmaf(h0, w0, acc);
        acc = fmaf(h1, w1, acc);
        acc = fmaf(h2, w2, acc);
        acc = fmaf(h3, w3, acc);
    }
    for (; i < e; ++i) {
        int ss = csr[i];
        acc = fmaf(h[(size_t)ss * 64 + lane], dinv[ss] * di, acc);
    }
    acc = fmaxf(acc + bias[lane], 0.f);
    out[(size_t)wid * 64 + lane] = f2bf(acc);
}

// ---------------- launch ----------------

extern "C" void kernel_launch(void* const* d_in, const int* in_sizes, int n_in,
                              void* d_out, int out_size, void* d_ws, size_t ws_size,
                              hipStream_t stream) {
    const float* x  = (const float*)d_in[0];
    const int*   ei = (const int*)d_in[1];   // int32 (JAX x64 disabled demotes int64)
    const float* W1 = (const float*)d_in[2];
    const float* b1 = (const float*)d_in[3];
    const float* W2 = (const float*)d_in[4];
    const float* b2 = (const float*)d_in[5];
    const float* W3 = (const float*)d_in[6];
    const float* b3 = (const float*)d_in[7];
    const float* W4 = (const float*)d_in[8];
    const float* b4 = (const float*)d_in[9];
    float* outp = (float*)d_out;

    const int N = NNODES;
    const int E = NEDGES;
    const int* srcp = ei;
    const int* dstp = ei + E;

    // workspace layout (aliased regions; stream-ordered lifetimes)
    char* w = (char*)d_ws;
    size_t o = 0;
    auto alloc = [&](size_t bytes) { size_t r = o; o = (o + bytes + 255) & ~(size_t)255; return r; };
    size_t cnt_off  = alloc((size_t)N * 4);
    size_t off_off  = alloc((size_t)N * 4);
    size_t dinv_off = alloc((size_t)N * 4);
    size_t bs_off   = alloc(256 * 4);
    size_t bse_off  = alloc(256 * 4);
    size_t csr_off  = alloc((size_t)E * 4);
    size_t hf_off   = alloc((size_t)N * 64 * 4);   // fp32 h; rank(u16, E) aliased at start (dead before gemm1)
    size_t xb_off   = alloc((size_t)N * 128 * 2);  // bf16 x; a_bf(N*64*2) aliased at start (x dead after gemm1)
    size_t wp1_off  = alloc(128 * 64 * 2);
    size_t wp2_off  = alloc(64 * 64 * 2);
    size_t wp34_off = alloc(64 * 64 * 2);
    size_t w34_off  = alloc(64 * 64 * 4);
    size_t b34_off  = alloc(64 * 4);

    int*            cnt  = (int*)(w + cnt_off);
    int*            off  = (int*)(w + off_off);
    float*          dinv = (float*)(w + dinv_off);
    int*            bs   = (int*)(w + bs_off);
    int*            bse  = (int*)(w + bse_off);
    int*            csr  = (int*)(w + csr_off);
    float*          hf   = (float*)(w + hf_off);
    unsigned short* rank = (unsigned short*)(w + hf_off);   // alias
    unsigned short* xb   = (unsigned short*)(w + xb_off);
    unsigned short* abf  = (unsigned short*)(w + xb_off);   // alias
    unsigned short* Wp1  = (unsigned short*)(w + wp1_off);
    unsigned short* Wp2  = (unsigned short*)(w + wp2_off);
    unsigned short* Wp34 = (unsigned short*)(w + wp34_off);
    float*          W34f = (float*)(w + w34_off);
    float*          b34  = (float*)(w + b34_off);

    hipMemsetAsync(w + cnt_off, 0, (size_t)N * 4, stream);

    const int eb = (E + 255) / 256;     // 6250
    const int nb = (N + 255) / 256;     // 391
    const int sb = (N + 1023) / 1024;   // 98

    count_kernel<<<eb, 256, 0, stream>>>(dstp, cnt, rank, E);
    dinv_kernel<<<nb, 256, 0, stream>>>(cnt, dinv, N);
    scan1_kernel<<<sb, 256, 0, stream>>>(cnt, off, bs, N);
    scan2_kernel<<<1, 256, 0, stream>>>(bs, bse, sb);
    scan3_kernel<<<nb, 256, 0, stream>>>(off, bse, N);
    scatter_kernel<<<eb, 256, 0, stream>>>(srcp, dstp, off, rank, csr, E);

    w34_kernel<<<65, 64, 0, stream>>>(W3, W4, b3, b4, W34f, b34);
    packW_kernel<128><<<(128 * 64 + 255) / 256, 256, 0, stream>>>(W1, Wp1);
    packW_kernel<64><<<(64 * 64 + 255) / 256, 256, 0, stream>>>(W2, Wp2);
    packW_kernel<64><<<(64 * 64 + 255) / 256, 256, 0, stream>>>(W34f, Wp34);
    tobf16_kernel<<<(N * 128 / 4 + 255) / 256, 256, 0, stream>>>(x, xb, N * 128);

    const int gb = (N + 63) / 64;       // 1563
    const int ab = (N + 3) / 4;         // 25000 (4 waves/block)

    // layer 1: mfma lin -> aggregate(+b1,relu, emit bf16)
    gemm_mfma_kernel<128, false><<<gb, 256, 0, stream>>>(xb, Wp1, nullptr, hf, N);
    aggregate_kernel<<<ab, 256, 0, stream>>>(hf, csr, off, cnt, dinv, b1, abf, N);
    // layer 2
    gemm_mfma_kernel<64, false><<<gb, 256, 0, stream>>>(abf, Wp2, nullptr, hf, N);
    aggregate_kernel<<<ab, 256, 0, stream>>>(hf, csr, off, cnt, dinv, b2, abf, N);
    // fused layers 3+4 + log_softmax
    gemm_mfma_kernel<64, true><<<gb, 256, 0, stream>>>(abf, Wp34, b34, outp, N);
}

// Round 3
// 391.866 us; speedup vs baseline: 1.4839x; 1.0355x over previous
//
#include <hip/hip_runtime.h>
#include <hip/hip_bf16.h>
#include <math.h>

#define NNODES 100000
#define NEDGES 1600000

typedef __bf16 bf16x8 __attribute__((ext_vector_type(8)));
typedef float f32x4 __attribute__((ext_vector_type(4)));

static __device__ inline unsigned short f2bf(float f) {
    __hip_bfloat16 h = __float2bfloat16(f);
    return *reinterpret_cast<unsigned short*>(&h);
}

static __device__ inline float bf2f(unsigned short u) {
    unsigned int x = ((unsigned int)u) << 16;
    return __builtin_bit_cast(float, x);
}

// ---------------- graph prep ----------------

// count + rank in one pass: rank[i] = slot of edge i within its dst bucket
__global__ __launch_bounds__(256) void count_kernel(const int* __restrict__ dst,
                                                    int* __restrict__ cnt,
                                                    unsigned short* __restrict__ rank, int E) {
    int i = blockIdx.x * 256 + threadIdx.x;
    if (i < E) {
        int r = atomicAdd(&cnt[dst[i]], 1);
        rank[i] = (unsigned short)r;
    }
}

__global__ __launch_bounds__(256) void dinv_kernel(const int* __restrict__ cnt,
                                                   float* __restrict__ dinv, int n) {
    int i = blockIdx.x * 256 + threadIdx.x;
    if (i < n) dinv[i] = rsqrtf((float)cnt[i] + 1.0f);
}

// per-block exclusive scan over 1024 elements (256 thr x 4)
__global__ __launch_bounds__(256) void scan1_kernel(const int* __restrict__ cnt,
                                                    int* __restrict__ off,
                                                    int* __restrict__ bsum, int n) {
    __shared__ int tmp[256];
    int tid = threadIdx.x;
    int t4 = blockIdx.x * 1024 + tid * 4;
    int v0 = (t4 + 0 < n) ? cnt[t4 + 0] : 0;
    int v1 = (t4 + 1 < n) ? cnt[t4 + 1] : 0;
    int v2 = (t4 + 2 < n) ? cnt[t4 + 2] : 0;
    int v3 = (t4 + 3 < n) ? cnt[t4 + 3] : 0;
    int ssum = v0 + v1 + v2 + v3;
    tmp[tid] = ssum;
    __syncthreads();
    for (int d = 1; d < 256; d <<= 1) {
        int x = (tid >= d) ? tmp[tid - d] : 0;
        __syncthreads();
        tmp[tid] += x;
        __syncthreads();
    }
    int run = tmp[tid] - ssum;  // exclusive prefix of this thread
    if (t4 + 0 < n) off[t4 + 0] = run; run += v0;
    if (t4 + 1 < n) off[t4 + 1] = run; run += v1;
    if (t4 + 2 < n) off[t4 + 2] = run; run += v2;
    if (t4 + 3 < n) off[t4 + 3] = run;
    if (tid == 255) bsum[blockIdx.x] = tmp[255];
}

__global__ __launch_bounds__(256) void scan2_kernel(const int* __restrict__ bsum,
                                                    int* __restrict__ bsum_ex, int nb) {
    __shared__ int tmp[256];
    int tid = threadIdx.x;
    int v = (tid < nb) ? bsum[tid] : 0;
    tmp[tid] = v;
    __syncthreads();
    for (int d = 1; d < 256; d <<= 1) {
        int x = (tid >= d) ? tmp[tid - d] : 0;
        __syncthreads();
        tmp[tid] += x;
        __syncthreads();
    }
    bsum_ex[tid] = tmp[tid] - v;  // exclusive
}

__global__ __launch_bounds__(256) void scan3_kernel(int* __restrict__ off,
                                                    const int* __restrict__ bsum_ex, int n) {
    int i = blockIdx.x * 256 + threadIdx.x;
    if (i < n) off[i] += bsum_ex[i >> 10];
}

// atomic-free scatter: position = off[dst] + precomputed rank
__global__ __launch_bounds__(256) void scatter_kernel(const int* __restrict__ src,
                                                      const int* __restrict__ dst,
                                                      const int* __restrict__ off,
                                                      const unsigned short* __restrict__ rank,
                                                      int* __restrict__ csr, int E) {
    int i = blockIdx.x * 256 + threadIdx.x;
    if (i < E) {
        int d = dst[i];
        csr[off[d] + (int)rank[i]] = src[i];
    }
}

// ---------------- W34 = W3 @ W4 (fp32), b34 = b3 @ W4 + b4 ----------------

__global__ __launch_bounds__(64) void w34_kernel(const float* __restrict__ W3,
                                                 const float* __restrict__ W4,
                                                 const float* __restrict__ b3,
                                                 const float* __restrict__ b4,
                                                 float* __restrict__ W34,
                                                 float* __restrict__ b34) {
    int j = threadIdx.x;
    int i = blockIdx.x;
    if (i < 64) {
        float a = 0.f;
        for (int k = 0; k < 256; ++k) a = fmaf(W3[i * 256 + k], W4[k * 64 + j], a);
        W34[i * 64 + j] = a;
    } else {
        float a = b4[j];
        for (int k = 0; k < 256; ++k) a = fmaf(b3[k], W4[k * 64 + j], a);
        b34[j] = a;
    }
}

// ---------------- pack W[K][64] fp32 -> bf16 B-fragment layout ----------------
// Wp[((t*S + s)*64 + lane)*8 + i] = W[k][ch], k = s*32 + (lane>>4)*8 + i, ch = t*16 + (lane&15)

template <int K>
__global__ __launch_bounds__(256) void packW_kernel(const float* __restrict__ W,
                                                    unsigned short* __restrict__ Wp) {
    constexpr int S = K / 32;
    int idx = blockIdx.x * 256 + threadIdx.x;
    if (idx >= 64 * K) return;
    int i = idx & 7;
    int rest = idx >> 3;
    int lane = rest & 63; rest >>= 6;
    int s = rest % S;
    int t = rest / S;
    int q = lane >> 4, lo = lane & 15;
    int k = s * 32 + q * 8 + i;
    int ch = t * 16 + lo;
    Wp[idx] = f2bf(W[k * 64 + ch]);
}

// ---------------- x fp32 -> bf16 ----------------

__global__ __launch_bounds__(256) void tobf16_kernel(const float* __restrict__ in,
                                                     unsigned short* __restrict__ outp, int nElem) {
    int i = blockIdx.x * 256 + threadIdx.x;
    int idx = i * 4;
    if (idx + 3 < nElem) {
        float4 v = *(const float4*)(in + idx);
        ushort4 o;
        o.x = f2bf(v.x); o.y = f2bf(v.y); o.z = f2bf(v.z); o.w = f2bf(v.w);
        *(ushort4*)(outp + idx) = o;
    }
}

// ---------------- MFMA GEMM: out[N,64] = Xbf[N,K] @ W[K,64] ----------------
// block = 256 thr = 4 waves; wave handles 16 nodes x 64 ch via 4 C-tiles of 16x16.
// A frag: lane holds X[node = base + (lane&15)][k = (lane>>4)*8 + j], j=0..7
// B frag from pre-packed Wp (lane-contiguous 16B loads, L1-resident)
// D: node = base + (lane>>4)*4 + reg, ch = t*16 + (lane&15)
// LSM=false: emit bf16 h' = h * dinv (pre-scaled for aggregation)
// LSM=true:  emit fp32 log_softmax(h + bias)

template <int K, bool LSM>
__global__ __launch_bounds__(256) void gemm_mfma_kernel(const unsigned short* __restrict__ Xb,
                                                        const unsigned short* __restrict__ Wp,
                                                        const float* __restrict__ bias,
                                                        const float* __restrict__ dinv,
                                                        unsigned short* __restrict__ outb,
                                                        float* __restrict__ outf, int n) {
    constexpr int S = K / 32;
    int w = threadIdx.x >> 6, lane = threadIdx.x & 63;
    int q = lane >> 4, lo = lane & 15;
    int base = blockIdx.x * 64 + w * 16;
    int nodeA = base + lo;
    int na = nodeA < n ? nodeA : 0;
    const unsigned short* xrow = Xb + (size_t)na * K + q * 8;

    f32x4 acc[4] = {};
#pragma unroll
    for (int s = 0; s < S; ++s) {
        bf16x8 a = *(const bf16x8*)(xrow + s * 32);
#pragma unroll
        for (int t = 0; t < 4; ++t) {
            bf16x8 b = *(const bf16x8*)(Wp + ((size_t)(t * S + s) * 64 + lane) * 8);
            acc[t] = __builtin_amdgcn_mfma_f32_16x16x32_bf16(a, b, acc[t], 0, 0, 0);
        }
    }

    if (!LSM) {
#pragma unroll
        for (int r = 0; r < 4; ++r) {
            int node = base + q * 4 + r;
            if (node < n) {
                float di = dinv[node];
#pragma unroll
                for (int t = 0; t < 4; ++t)
                    outb[(size_t)node * 64 + t * 16 + lo] = f2bf(acc[t][r] * di);
            }
        }
    } else {
        // fused bias + log_softmax over 64 channels
#pragma unroll
        for (int r = 0; r < 4; ++r) {
            int node = base + q * 4 + r;
            float v0 = acc[0][r] + bias[0 * 16 + lo];
            float v1 = acc[1][r] + bias[1 * 16 + lo];
            float v2 = acc[2][r] + bias[2 * 16 + lo];
            float v3 = acc[3][r] + bias[3 * 16 + lo];
            float mx = fmaxf(fmaxf(v0, v1), fmaxf(v2, v3));
            for (int d = 1; d < 16; d <<= 1) mx = fmaxf(mx, __shfl_xor(mx, d));
            float sm = __expf(v0 - mx) + __expf(v1 - mx) + __expf(v2 - mx) + __expf(v3 - mx);
            for (int d = 1; d < 16; d <<= 1) sm += __shfl_xor(sm, d);
            float lse = mx + __logf(sm);
            if (node < n) {
                outf[(size_t)node * 64 + 0 * 16 + lo] = v0 - lse;
                outf[(size_t)node * 64 + 1 * 16 + lo] = v1 - lse;
                outf[(size_t)node * 64 + 2 * 16 + lo] = v2 - lse;
                outf[(size_t)node * 64 + 3 * 16 + lo] = v3 - lse;
            }
        }
    }
}

// ---------------- aggregation: one wave per dst node, 64 lanes = 64 ch ----------------
// h' rows are bf16, pre-scaled by dinv[src]. out[dst] = relu(dinv[dst]*(sum h'[src] + h'[dst]) + b)

__global__ __launch_bounds__(256) void aggregate_kernel(const unsigned short* __restrict__ hp,
                                                        const int* __restrict__ csr,
                                                        const int* __restrict__ off,
                                                        const int* __restrict__ cnt,
                                                        const float* __restrict__ dinv,
                                                        const float* __restrict__ bias,
                                                        unsigned short* __restrict__ out, int n) {
    int wid = (blockIdx.x * 256 + threadIdx.x) >> 6;
    int lane = threadIdx.x & 63;
    if (wid >= n) return;
    float acc = bf2f(hp[(size_t)wid * 64 + lane]);  // self-loop term h'[dst]
    int s = off[wid];
    int e = s + cnt[wid];
    int i = s;
    for (; i + 8 <= e; i += 8) {
        int s0 = csr[i + 0], s1 = csr[i + 1], s2 = csr[i + 2], s3 = csr[i + 3];
        int s4 = csr[i + 4], s5 = csr[i + 5], s6 = csr[i + 6], s7 = csr[i + 7];
        float h0 = bf2f(hp[(size_t)s0 * 64 + lane]);
        float h1 = bf2f(hp[(size_t)s1 * 64 + lane]);
        float h2 = bf2f(hp[(size_t)s2 * 64 + lane]);
        float h3 = bf2f(hp[(size_t)s3 * 64 + lane]);
        float h4 = bf2f(hp[(size_t)s4 * 64 + lane]);
        float h5 = bf2f(hp[(size_t)s5 * 64 + lane]);
        float h6 = bf2f(hp[(size_t)s6 * 64 + lane]);
        float h7 = bf2f(hp[(size_t)s7 * 64 + lane]);
        acc += ((h0 + h1) + (h2 + h3)) + ((h4 + h5) + (h6 + h7));
    }
    for (; i < e; ++i) {
        acc += bf2f(hp[(size_t)csr[i] * 64 + lane]);
    }
    acc = fmaxf(fmaf(acc, dinv[wid], bias[lane]), 0.f);
    out[(size_t)wid * 64 + lane] = f2bf(acc);
}

// ---------------- launch ----------------

extern "C" void kernel_launch(void* const* d_in, const int* in_sizes, int n_in,
                              void* d_out, int out_size, void* d_ws, size_t ws_size,
                              hipStream_t stream) {
    const float* x  = (const float*)d_in[0];
    const int*   ei = (const int*)d_in[1];   // int32 (JAX x64 disabled demotes int64)
    const float* W1 = (const float*)d_in[2];
    const float* b1 = (const float*)d_in[3];
    const float* W2 = (const float*)d_in[4];
    const float* b2 = (const float*)d_in[5];
    const float* W3 = (const float*)d_in[6];
    const float* b3 = (const float*)d_in[7];
    const float* W4 = (const float*)d_in[8];
    const float* b4 = (const float*)d_in[9];
    float* outp = (float*)d_out;

    const int N = NNODES;
    const int E = NEDGES;
    const int* srcp = ei;
    const int* dstp = ei + E;

    // workspace layout (aliased regions; stream-ordered lifetimes)
    char* w = (char*)d_ws;
    size_t o = 0;
    auto alloc = [&](size_t bytes) { size_t r = o; o = (o + bytes + 255) & ~(size_t)255; return r; };
    size_t cnt_off  = alloc((size_t)N * 4);
    size_t off_off  = alloc((size_t)N * 4);
    size_t dinv_off = alloc((size_t)N * 4);
    size_t bs_off   = alloc(256 * 4);
    size_t bse_off  = alloc(256 * 4);
    size_t csr_off  = alloc((size_t)E * 4);
    size_t hp_off   = alloc((size_t)N * 64 * 2);   // bf16 h'; rank(u16, E=3.2MB) aliased (dead before gemm1)
    size_t xb_off   = alloc((size_t)N * 128 * 2);  // bf16 x; abf(N*64*2) aliased (x dead after gemm1)
    size_t wp1_off  = alloc(128 * 64 * 2);
    size_t wp2_off  = alloc(64 * 64 * 2);
    size_t wp34_off = alloc(64 * 64 * 2);
    size_t w34_off  = alloc(64 * 64 * 4);
    size_t b34_off  = alloc(64 * 4);

    int*            cnt  = (int*)(w + cnt_off);
    int*            off  = (int*)(w + off_off);
    float*          dinv = (float*)(w + dinv_off);
    int*            bs   = (int*)(w + bs_off);
    int*            bse  = (int*)(w + bse_off);
    int*            csr  = (int*)(w + csr_off);
    unsigned short* hp   = (unsigned short*)(w + hp_off);
    unsigned short* rank = (unsigned short*)(w + hp_off);   // alias
    unsigned short* xb   = (unsigned short*)(w + xb_off);
    unsigned short* abf  = (unsigned short*)(w + xb_off);   // alias
    unsigned short* Wp1  = (unsigned short*)(w + wp1_off);
    unsigned short* Wp2  = (unsigned short*)(w + wp2_off);
    unsigned short* Wp34 = (unsigned short*)(w + wp34_off);
    float*          W34f = (float*)(w + w34_off);
    float*          b34  = (float*)(w + b34_off);

    hipMemsetAsync(w + cnt_off, 0, (size_t)N * 4, stream);

    const int eb = (E + 255) / 256;     // 6250
    const int nb = (N + 255) / 256;     // 391
    const int sb = (N + 1023) / 1024;   // 98

    count_kernel<<<eb, 256, 0, stream>>>(dstp, cnt, rank, E);
    dinv_kernel<<<nb, 256, 0, stream>>>(cnt, dinv, N);
    scan1_kernel<<<sb, 256, 0, stream>>>(cnt, off, bs, N);
    scan2_kernel<<<1, 256, 0, stream>>>(bs, bse, sb);
    scan3_kernel<<<nb, 256, 0, stream>>>(off, bse, N);
    scatter_kernel<<<eb, 256, 0, stream>>>(srcp, dstp, off, rank, csr, E);

    w34_kernel<<<65, 64, 0, stream>>>(W3, W4, b3, b4, W34f, b34);
    packW_kernel<128><<<(128 * 64 + 255) / 256, 256, 0, stream>>>(W1, Wp1);
    packW_kernel<64><<<(64 * 64 + 255) / 256, 256, 0, stream>>>(W2, Wp2);
    packW_kernel<64><<<(64 * 64 + 255) / 256, 256, 0, stream>>>(W34f, Wp34);
    tobf16_kernel<<<(N * 128 / 4 + 255) / 256, 256, 0, stream>>>(x, xb, N * 128);

    const int gb = (N + 63) / 64;       // 1563
    const int ab = (N + 3) / 4;         // 25000 (4 waves/block)

    // layer 1: mfma lin (emit bf16 h*dinv) -> aggregate(+b1,relu, emit bf16)
    gemm_mfma_kernel<128, false><<<gb, 256, 0, stream>>>(xb, Wp1, nullptr, dinv, hp, nullptr, N);
    aggregate_kernel<<<ab, 256, 0, stream>>>(hp, csr, off, cnt, dinv, b1, abf, N);
    // layer 2
    gemm_mfma_kernel<64, false><<<gb, 256, 0, stream>>>(abf, Wp2, nullptr, dinv, hp, nullptr, N);
    aggregate_kernel<<<ab, 256, 0, stream>>>(hp, csr, off, cnt, dinv, b2, abf, N);
    // fused layers 3+4 + log_softmax
    gemm_mfma_kernel<64, true><<<gb, 256, 0, stream>>>(abf, Wp34, b34, nullptr, nullptr, outp, N);
}

// Round 4
// 330.482 us; speedup vs baseline: 1.7595x; 1.1857x over previous
//
#include <hip/hip_runtime.h>
#include <hip/hip_bf16.h>
#include <math.h>

#define NNODES 100000
#define NEDGES 1600000
#define NB 782           // ceil(NNODES/128) buckets of 128 nodes
#define PB 256           // partition blocks
#define EPB 6250         // NEDGES / PB exactly
#define SCAN_N (NB * PB) // 200192
#define CAP 4608         // LDS stage capacity per bucket (avg 2048, max ~2300)

typedef __bf16 bf16x8 __attribute__((ext_vector_type(8)));
typedef float f32x4 __attribute__((ext_vector_type(4)));

static __device__ inline unsigned short f2bf(float f) {
    __hip_bfloat16 h = __float2bfloat16(f);
    return *reinterpret_cast<unsigned short*>(&h);
}

static __device__ inline float bf2f(unsigned short u) {
    unsigned int x = ((unsigned int)u) << 16;
    return __builtin_bit_cast(float, x);
}

// ---------------- pass A: per-block LDS histogram of dst>>7 ----------------
// histg[bucket*PB + blk] = #edges in blk's chunk with dst in bucket. No global atomics.

__global__ __launch_bounds__(256) void hist_kernel(const int* __restrict__ dst,
                                                   int* __restrict__ histg) {
    __shared__ int h[NB];
    int tid = threadIdx.x, blk = blockIdx.x;
    for (int b = tid; b < NB; b += 256) h[b] = 0;
    __syncthreads();
    int base = blk * EPB;
    for (int i = base + tid; i < base + EPB; i += 256)
        atomicAdd(&h[dst[i] >> 7], 1);
    __syncthreads();
    for (int b = tid; b < NB; b += 256) histg[b * PB + blk] = h[b];
}

// ---------------- scan chain over SCAN_N elements ----------------

__global__ __launch_bounds__(256) void scan1_kernel(const int* __restrict__ cnt,
                                                    int* __restrict__ off,
                                                    int* __restrict__ bsum, int n) {
    __shared__ int tmp[256];
    int tid = threadIdx.x;
    int t4 = blockIdx.x * 1024 + tid * 4;
    int v0 = (t4 + 0 < n) ? cnt[t4 + 0] : 0;
    int v1 = (t4 + 1 < n) ? cnt[t4 + 1] : 0;
    int v2 = (t4 + 2 < n) ? cnt[t4 + 2] : 0;
    int v3 = (t4 + 3 < n) ? cnt[t4 + 3] : 0;
    int ssum = v0 + v1 + v2 + v3;
    tmp[tid] = ssum;
    __syncthreads();
    for (int d = 1; d < 256; d <<= 1) {
        int x = (tid >= d) ? tmp[tid - d] : 0;
        __syncthreads();
        tmp[tid] += x;
        __syncthreads();
    }
    int run = tmp[tid] - ssum;
    if (t4 + 0 < n) off[t4 + 0] = run; run += v0;
    if (t4 + 1 < n) off[t4 + 1] = run; run += v1;
    if (t4 + 2 < n) off[t4 + 2] = run; run += v2;
    if (t4 + 3 < n) off[t4 + 3] = run;
    if (tid == 255) bsum[blockIdx.x] = tmp[255];
}

__global__ __launch_bounds__(256) void scan2_kernel(const int* __restrict__ bsum,
                                                    int* __restrict__ bsum_ex, int nb) {
    __shared__ int tmp[256];
    int tid = threadIdx.x;
    int v = (tid < nb) ? bsum[tid] : 0;
    tmp[tid] = v;
    __syncthreads();
    for (int d = 1; d < 256; d <<= 1) {
        int x = (tid >= d) ? tmp[tid - d] : 0;
        __syncthreads();
        tmp[tid] += x;
        __syncthreads();
    }
    bsum_ex[tid] = tmp[tid] - v;
}

// finalize scan + emit transposed table gbaseT[blk*NB + bucket]
__global__ __launch_bounds__(256) void scan3t_kernel(const int* __restrict__ part_scan,
                                                     const int* __restrict__ bsum_ex,
                                                     int* __restrict__ gbaseT, int n) {
    int i = blockIdx.x * 256 + threadIdx.x;
    if (i < n) {
        int v = part_scan[i] + bsum_ex[i >> 10];
        int b = i >> 8, blk = i & 255;
        gbaseT[blk * NB + b] = v;
    }
}

// ---------------- pass B: partition edges into bucket-ordered array ----------------
// packed u32: (dst&127)<<17 | src   (src < 2^17)

__global__ __launch_bounds__(256) void part_kernel(const int* __restrict__ src,
                                                   const int* __restrict__ dst,
                                                   const int* __restrict__ gbaseT,
                                                   unsigned int* __restrict__ part) {
    __shared__ int gcol[NB];
    __shared__ int cur[NB];
    int tid = threadIdx.x, blk = blockIdx.x;
    for (int b = tid; b < NB; b += 256) {
        gcol[b] = gbaseT[blk * NB + b];
        cur[b] = 0;
    }
    __syncthreads();
    int base = blk * EPB;
    for (int i = base + tid; i < base + EPB; i += 256) {
        int s = src[i], d = dst[i];
        int bkt = d >> 7;
        int r = atomicAdd(&cur[bkt], 1);
        part[gcol[bkt] + r] = ((unsigned int)(d & 127) << 17) | (unsigned int)s;
    }
}

// ---------------- pass C: per-bucket CSR build + cnt/off/dinv ----------------

__global__ __launch_bounds__(256) void csr_kernel(const unsigned int* __restrict__ part,
                                                  const int* __restrict__ gbaseT,
                                                  int* __restrict__ csr,
                                                  int* __restrict__ cnt_g,
                                                  int* __restrict__ off_g,
                                                  float* __restrict__ dinv_g, int n) {
    __shared__ unsigned int stage[CAP];
    __shared__ int hist2[128];
    __shared__ int sc[128];
    __shared__ int excl[128];
    __shared__ int cur2[128];
    int tid = threadIdx.x, b = blockIdx.x;
    int S = gbaseT[b];
    int T = (b == NB - 1) ? NEDGES : gbaseT[b + 1];
    int len = T - S;
    bool fit = (len <= CAP);
    if (tid < 128) { hist2[tid] = 0; cur2[tid] = 0; }
    __syncthreads();
    for (int i = tid; i < len; i += 256) {
        unsigned int p = part[S + i];
        if (fit) stage[i] = p;
        atomicAdd(&hist2[p >> 17], 1);
    }
    __syncthreads();
    if (tid < 128) sc[tid] = hist2[tid];
    __syncthreads();
    for (int d = 1; d < 128; d <<= 1) {
        int x = 0;
        if (tid < 128 && tid >= d) x = sc[tid - d];
        __syncthreads();
        if (tid < 128) sc[tid] += x;
        __syncthreads();
    }
    if (tid < 128) {
        int c = hist2[tid];
        int ex = sc[tid] - c;
        excl[tid] = ex;
        int node = b * 128 + tid;
        if (node < n) {
            cnt_g[node] = c;
            off_g[node] = S + ex;
            dinv_g[node] = rsqrtf((float)c + 1.0f);
        }
    }
    __syncthreads();
    for (int i = tid; i < len; i += 256) {
        unsigned int p = fit ? stage[i] : part[S + i];
        int dl = p >> 17;
        int s = (int)(p & 0x1FFFFu);
        int r = atomicAdd(&cur2[dl], 1);
        csr[S + excl[dl] + r] = s;
    }
}

// ---------------- W34 = W3 @ W4 (fp32), b34 = b3 @ W4 + b4 ----------------

__global__ __launch_bounds__(64) void w34_kernel(const float* __restrict__ W3,
                                                 const float* __restrict__ W4,
                                                 const float* __restrict__ b3,
                                                 const float* __restrict__ b4,
                                                 float* __restrict__ W34,
                                                 float* __restrict__ b34) {
    int j = threadIdx.x;
    int i = blockIdx.x;
    if (i < 64) {
        float a = 0.f;
        for (int k = 0; k < 256; ++k) a = fmaf(W3[i * 256 + k], W4[k * 64 + j], a);
        W34[i * 64 + j] = a;
    } else {
        float a = b4[j];
        for (int k = 0; k < 256; ++k) a = fmaf(b3[k], W4[k * 64 + j], a);
        b34[j] = a;
    }
}

// ---------------- pack W[K][64] fp32 -> bf16 B-fragment layout ----------------

template <int K>
__global__ __launch_bounds__(256) void packW_kernel(const float* __restrict__ W,
                                                    unsigned short* __restrict__ Wp) {
    constexpr int S = K / 32;
    int idx = blockIdx.x * 256 + threadIdx.x;
    if (idx >= 64 * K) return;
    int i = idx & 7;
    int rest = idx >> 3;
    int lane = rest & 63; rest >>= 6;
    int s = rest % S;
    int t = rest / S;
    int q = lane >> 4, lo = lane & 15;
    int k = s * 32 + q * 8 + i;
    int ch = t * 16 + lo;
    Wp[idx] = f2bf(W[k * 64 + ch]);
}

// ---------------- MFMA GEMM: out[N,64] = X[N,K] @ W[K,64] ----------------
// F32IN: read fp32 X, convert to bf16 in-register (layer 1, saves a conversion pass)
// LSM=false: emit bf16 h' = h * dinv;  LSM=true: emit fp32 log_softmax(h + bias)

template <int K, bool LSM, bool F32IN>
__global__ __launch_bounds__(256) void gemm_mfma_kernel(const unsigned short* __restrict__ Xb,
                                                        const float* __restrict__ Xf,
                                                        const unsigned short* __restrict__ Wp,
                                                        const float* __restrict__ bias,
                                                        const float* __restrict__ dinv,
                                                        unsigned short* __restrict__ outb,
                                                        float* __restrict__ outf, int n) {
    constexpr int S = K / 32;
    int w = threadIdx.x >> 6, lane = threadIdx.x & 63;
    int q = lane >> 4, lo = lane & 15;
    int base = blockIdx.x * 64 + w * 16;
    int nodeA = base + lo;
    int na = nodeA < n ? nodeA : 0;

    f32x4 acc[4] = {};
#pragma unroll
    for (int s = 0; s < S; ++s) {
        bf16x8 a;
        if (F32IN) {
            const float* xr = Xf + (size_t)na * K + q * 8 + s * 32;
            float4 u = *(const float4*)(xr);
            float4 v = *(const float4*)(xr + 4);
            a[0] = (__bf16)u.x; a[1] = (__bf16)u.y; a[2] = (__bf16)u.z; a[3] = (__bf16)u.w;
            a[4] = (__bf16)v.x; a[5] = (__bf16)v.y; a[6] = (__bf16)v.z; a[7] = (__bf16)v.w;
        } else {
            a = *(const bf16x8*)(Xb + (size_t)na * K + q * 8 + s * 32);
        }
#pragma unroll
        for (int t = 0; t < 4; ++t) {
            bf16x8 b = *(const bf16x8*)(Wp + ((size_t)(t * S + s) * 64 + lane) * 8);
            acc[t] = __builtin_amdgcn_mfma_f32_16x16x32_bf16(a, b, acc[t], 0, 0, 0);
        }
    }

    if (!LSM) {
#pragma unroll
        for (int r = 0; r < 4; ++r) {
            int node = base + q * 4 + r;
            if (node < n) {
                float di = dinv[node];
#pragma unroll
                for (int t = 0; t < 4; ++t)
                    outb[(size_t)node * 64 + t * 16 + lo] = f2bf(acc[t][r] * di);
            }
        }
    } else {
#pragma unroll
        for (int r = 0; r < 4; ++r) {
            int node = base + q * 4 + r;
            float v0 = acc[0][r] + bias[0 * 16 + lo];
            float v1 = acc[1][r] + bias[1 * 16 + lo];
            float v2 = acc[2][r] + bias[2 * 16 + lo];
            float v3 = acc[3][r] + bias[3 * 16 + lo];
            float mx = fmaxf(fmaxf(v0, v1), fmaxf(v2, v3));
            for (int d = 1; d < 16; d <<= 1) mx = fmaxf(mx, __shfl_xor(mx, d));
            float sm = __expf(v0 - mx) + __expf(v1 - mx) + __expf(v2 - mx) + __expf(v3 - mx);
            for (int d = 1; d < 16; d <<= 1) sm += __shfl_xor(sm, d);
            float lse = mx + __logf(sm);
            if (node < n) {
                outf[(size_t)node * 64 + 0 * 16 + lo] = v0 - lse;
                outf[(size_t)node * 64 + 1 * 16 + lo] = v1 - lse;
                outf[(size_t)node * 64 + 2 * 16 + lo] = v2 - lse;
                outf[(size_t)node * 64 + 3 * 16 + lo] = v3 - lse;
            }
        }
    }
}

// ---------------- aggregation: one wave per dst node, 64 lanes = 64 ch ----------------

__global__ __launch_bounds__(256) void aggregate_kernel(const unsigned short* __restrict__ hp,
                                                        const int* __restrict__ csr,
                                                        const int* __restrict__ off,
                                                        const int* __restrict__ cnt,
                                                        const float* __restrict__ dinv,
                                                        const float* __restrict__ bias,
                                                        unsigned short* __restrict__ out, int n) {
    int wid = (blockIdx.x * 256 + threadIdx.x) >> 6;
    int lane = threadIdx.x & 63;
    if (wid >= n) return;
    float acc = bf2f(hp[(size_t)wid * 64 + lane]);  // self-loop term h'[dst]
    int s = off[wid];
    int e = s + cnt[wid];
    int i = s;
    for (; i + 8 <= e; i += 8) {
        int s0 = csr[i + 0], s1 = csr[i + 1], s2 = csr[i + 2], s3 = csr[i + 3];
        int s4 = csr[i + 4], s5 = csr[i + 5], s6 = csr[i + 6], s7 = csr[i + 7];
        float h0 = bf2f(hp[(size_t)s0 * 64 + lane]);
        float h1 = bf2f(hp[(size_t)s1 * 64 + lane]);
        float h2 = bf2f(hp[(size_t)s2 * 64 + lane]);
        float h3 = bf2f(hp[(size_t)s3 * 64 + lane]);
        float h4 = bf2f(hp[(size_t)s4 * 64 + lane]);
        float h5 = bf2f(hp[(size_t)s5 * 64 + lane]);
        float h6 = bf2f(hp[(size_t)s6 * 64 + lane]);
        float h7 = bf2f(hp[(size_t)s7 * 64 + lane]);
        acc += ((h0 + h1) + (h2 + h3)) + ((h4 + h5) + (h6 + h7));
    }
    for (; i < e; ++i) {
        acc += bf2f(hp[(size_t)csr[i] * 64 + lane]);
    }
    acc = fmaxf(fmaf(acc, dinv[wid], bias[lane]), 0.f);
    out[(size_t)wid * 64 + lane] = f2bf(acc);
}

// ---------------- launch ----------------

extern "C" void kernel_launch(void* const* d_in, const int* in_sizes, int n_in,
                              void* d_out, int out_size, void* d_ws, size_t ws_size,
                              hipStream_t stream) {
    const float* x  = (const float*)d_in[0];
    const int*   ei = (const int*)d_in[1];   // int32 (JAX x64 disabled demotes int64)
    const float* W1 = (const float*)d_in[2];
    const float* b1 = (const float*)d_in[3];
    const float* W2 = (const float*)d_in[4];
    const float* b2 = (const float*)d_in[5];
    const float* W3 = (const float*)d_in[6];
    const float* b3 = (const float*)d_in[7];
    const float* W4 = (const float*)d_in[8];
    const float* b4 = (const float*)d_in[9];
    float* outp = (float*)d_out;

    const int N = NNODES;
    const int E = NEDGES;
    const int* srcp = ei;
    const int* dstp = ei + E;

    char* w = (char*)d_ws;
    size_t o = 0;
    auto alloc = [&](size_t bytes) { size_t r = o; o = (o + bytes + 255) & ~(size_t)255; return r; };
    size_t cnt_off   = alloc((size_t)N * 4);
    size_t off_off   = alloc((size_t)N * 4);
    size_t dinv_off  = alloc((size_t)N * 4);
    size_t histg_off = alloc((size_t)SCAN_N * 4);
    size_t gscan_off = alloc((size_t)SCAN_N * 4);
    size_t gbT_off   = alloc((size_t)SCAN_N * 4);
    size_t bs_off    = alloc(256 * 4);
    size_t bse_off   = alloc(256 * 4);
    size_t part_off  = alloc((size_t)E * 4);
    size_t csr_off   = alloc((size_t)E * 4);
    size_t hp_off    = alloc((size_t)N * 64 * 2);
    size_t abf_off   = alloc((size_t)N * 64 * 2);
    size_t wp1_off   = alloc(128 * 64 * 2);
    size_t wp2_off   = alloc(64 * 64 * 2);
    size_t wp34_off  = alloc(64 * 64 * 2);
    size_t w34_off   = alloc(64 * 64 * 4);
    size_t b34_off   = alloc(64 * 4);

    int*            cnt   = (int*)(w + cnt_off);
    int*            off   = (int*)(w + off_off);
    float*          dinv  = (float*)(w + dinv_off);
    int*            histg = (int*)(w + histg_off);
    int*            gscan = (int*)(w + gscan_off);
    int*            gbT   = (int*)(w + gbT_off);
    int*            bs    = (int*)(w + bs_off);
    int*            bse   = (int*)(w + bse_off);
    unsigned int*   part  = (unsigned int*)(w + part_off);
    int*            csr   = (int*)(w + csr_off);
    unsigned short* hp    = (unsigned short*)(w + hp_off);
    unsigned short* abf   = (unsigned short*)(w + abf_off);
    unsigned short* Wp1   = (unsigned short*)(w + wp1_off);
    unsigned short* Wp2   = (unsigned short*)(w + wp2_off);
    unsigned short* Wp34  = (unsigned short*)(w + wp34_off);
    float*          W34f  = (float*)(w + w34_off);
    float*          b34   = (float*)(w + b34_off);

    const int sb = (SCAN_N + 1023) / 1024;   // 196
    const int s3b = (SCAN_N + 255) / 256;    // 783

    // CSR build: hist -> scan -> partition -> per-bucket counting sort. No global atomics.
    hist_kernel<<<PB, 256, 0, stream>>>(dstp, histg);
    scan1_kernel<<<sb, 256, 0, stream>>>(histg, gscan, bs, SCAN_N);
    scan2_kernel<<<1, 256, 0, stream>>>(bs, bse, sb);
    scan3t_kernel<<<s3b, 256, 0, stream>>>(gscan, bse, gbT, SCAN_N);
    part_kernel<<<PB, 256, 0, stream>>>(srcp, dstp, gbT, part);
    csr_kernel<<<NB, 256, 0, stream>>>(part, gbT, csr, cnt, off, dinv, N);

    w34_kernel<<<65, 64, 0, stream>>>(W3, W4, b3, b4, W34f, b34);
    packW_kernel<128><<<(128 * 64 + 255) / 256, 256, 0, stream>>>(W1, Wp1);
    packW_kernel<64><<<(64 * 64 + 255) / 256, 256, 0, stream>>>(W2, Wp2);
    packW_kernel<64><<<(64 * 64 + 255) / 256, 256, 0, stream>>>(W34f, Wp34);

    const int gb = (N + 63) / 64;       // 1563
    const int ab = (N + 3) / 4;         // 25000

    // layer 1: mfma lin (fp32 x in-register cvt, emit bf16 h*dinv) -> aggregate
    gemm_mfma_kernel<128, false, true><<<gb, 256, 0, stream>>>(nullptr, x, Wp1, nullptr, dinv, hp, nullptr, N);
    aggregate_kernel<<<ab, 256, 0, stream>>>(hp, csr, off, cnt, dinv, b1, abf, N);
    // layer 2
    gemm_mfma_kernel<64, false, false><<<gb, 256, 0, stream>>>(abf, nullptr, Wp2, nullptr, dinv, hp, nullptr, N);
    aggregate_kernel<<<ab, 256, 0, stream>>>(hp, csr, off, cnt, dinv, b2, abf, N);
    // fused layers 3+4 + log_softmax
    gemm_mfma_kernel<64, true, false><<<gb, 256, 0, stream>>>(abf, nullptr, Wp34, b34, nullptr, nullptr, outp, N);
}

// Round 5
// 309.691 us; speedup vs baseline: 1.8776x; 1.0671x over previous
//
#include <hip/hip_runtime.h>
#include <hip/hip_bf16.h>
#include <math.h>

#define NNODES 100000
#define NEDGES 1600000
#define NB 782           // ceil(NNODES/128) buckets of 128 nodes
#define PB 256           // partition blocks
#define EPB 6250         // NEDGES / PB exactly
#define SCAN_N (NB * PB) // 200192
#define CAP 4608         // LDS stage capacity per bucket (avg 2048, max ~2300)

typedef __bf16 bf16x8 __attribute__((ext_vector_type(8)));
typedef float f32x4 __attribute__((ext_vector_type(4)));

static __device__ inline unsigned short f2bf(float f) {
    __hip_bfloat16 h = __float2bfloat16(f);
    return *reinterpret_cast<unsigned short*>(&h);
}

static __device__ inline float bf2f(unsigned short u) {
    unsigned int x = ((unsigned int)u) << 16;
    return __builtin_bit_cast(float, x);
}

// ---------------- pass A: per-block LDS histogram of dst>>7 ----------------

__global__ __launch_bounds__(256) void hist_kernel(const int* __restrict__ dst,
                                                   int* __restrict__ histg) {
    __shared__ int h[NB];
    int tid = threadIdx.x, blk = blockIdx.x;
    for (int b = tid; b < NB; b += 256) h[b] = 0;
    __syncthreads();
    int base = blk * EPB;
    for (int i = base + tid; i < base + EPB; i += 256)
        atomicAdd(&h[dst[i] >> 7], 1);
    __syncthreads();
    for (int b = tid; b < NB; b += 256) histg[b * PB + blk] = h[b];
}

// ---------------- scan chain over SCAN_N elements ----------------

__global__ __launch_bounds__(256) void scan1_kernel(const int* __restrict__ cnt,
                                                    int* __restrict__ off,
                                                    int* __restrict__ bsum, int n) {
    __shared__ int tmp[256];
    int tid = threadIdx.x;
    int t4 = blockIdx.x * 1024 + tid * 4;
    int v0 = (t4 + 0 < n) ? cnt[t4 + 0] : 0;
    int v1 = (t4 + 1 < n) ? cnt[t4 + 1] : 0;
    int v2 = (t4 + 2 < n) ? cnt[t4 + 2] : 0;
    int v3 = (t4 + 3 < n) ? cnt[t4 + 3] : 0;
    int ssum = v0 + v1 + v2 + v3;
    tmp[tid] = ssum;
    __syncthreads();
    for (int d = 1; d < 256; d <<= 1) {
        int x = (tid >= d) ? tmp[tid - d] : 0;
        __syncthreads();
        tmp[tid] += x;
        __syncthreads();
    }
    int run = tmp[tid] - ssum;
    if (t4 + 0 < n) off[t4 + 0] = run; run += v0;
    if (t4 + 1 < n) off[t4 + 1] = run; run += v1;
    if (t4 + 2 < n) off[t4 + 2] = run; run += v2;
    if (t4 + 3 < n) off[t4 + 3] = run;
    if (tid == 255) bsum[blockIdx.x] = tmp[255];
}

__global__ __launch_bounds__(256) void scan2_kernel(const int* __restrict__ bsum,
                                                    int* __restrict__ bsum_ex, int nb) {
    __shared__ int tmp[256];
    int tid = threadIdx.x;
    int v = (tid < nb) ? bsum[tid] : 0;
    tmp[tid] = v;
    __syncthreads();
    for (int d = 1; d < 256; d <<= 1) {
        int x = (tid >= d) ? tmp[tid - d] : 0;
        __syncthreads();
        tmp[tid] += x;
        __syncthreads();
    }
    bsum_ex[tid] = tmp[tid] - v;
}

__global__ __launch_bounds__(256) void scan3t_kernel(const int* __restrict__ part_scan,
                                                     const int* __restrict__ bsum_ex,
                                                     int* __restrict__ gbaseT, int n) {
    int i = blockIdx.x * 256 + threadIdx.x;
    if (i < n) {
        int v = part_scan[i] + bsum_ex[i >> 10];
        int b = i >> 8, blk = i & 255;
        gbaseT[blk * NB + b] = v;
    }
}

// ---------------- pass B: partition edges into bucket-ordered array ----------------

__global__ __launch_bounds__(256) void part_kernel(const int* __restrict__ src,
                                                   const int* __restrict__ dst,
                                                   const int* __restrict__ gbaseT,
                                                   unsigned int* __restrict__ part) {
    __shared__ int gcol[NB];
    __shared__ int cur[NB];
    int tid = threadIdx.x, blk = blockIdx.x;
    for (int b = tid; b < NB; b += 256) {
        gcol[b] = gbaseT[blk * NB + b];
        cur[b] = 0;
    }
    __syncthreads();
    int base = blk * EPB;
    for (int i = base + tid; i < base + EPB; i += 256) {
        int s = src[i], d = dst[i];
        int bkt = d >> 7;
        int r = atomicAdd(&cur[bkt], 1);
        part[gcol[bkt] + r] = ((unsigned int)(d & 127) << 17) | (unsigned int)s;
    }
}

// ---------------- pass C: per-bucket CSR build + cnt/off/dinv ----------------

__global__ __launch_bounds__(256) void csr_kernel(const unsigned int* __restrict__ part,
                                                  const int* __restrict__ gbaseT,
                                                  int* __restrict__ csr,
                                                  int* __restrict__ cnt_g,
                                                  int* __restrict__ off_g,
                                                  float* __restrict__ dinv_g, int n) {
    __shared__ unsigned int stage[CAP];
    __shared__ int hist2[128];
    __shared__ int sc[128];
    __shared__ int excl[128];
    __shared__ int cur2[128];
    int tid = threadIdx.x, b = blockIdx.x;
    int S = gbaseT[b];
    int T = (b == NB - 1) ? NEDGES : gbaseT[b + 1];
    int len = T - S;
    bool fit = (len <= CAP);
    if (tid < 128) { hist2[tid] = 0; cur2[tid] = 0; }
    __syncthreads();
    for (int i = tid; i < len; i += 256) {
        unsigned int p = part[S + i];
        if (fit) stage[i] = p;
        atomicAdd(&hist2[p >> 17], 1);
    }
    __syncthreads();
    if (tid < 128) sc[tid] = hist2[tid];
    __syncthreads();
    for (int d = 1; d < 128; d <<= 1) {
        int x = 0;
        if (tid < 128 && tid >= d) x = sc[tid - d];
        __syncthreads();
        if (tid < 128) sc[tid] += x;
        __syncthreads();
    }
    if (tid < 128) {
        int c = hist2[tid];
        int ex = sc[tid] - c;
        excl[tid] = ex;
        int node = b * 128 + tid;
        if (node < n) {
            cnt_g[node] = c;
            off_g[node] = S + ex;
            dinv_g[node] = rsqrtf((float)c + 1.0f);
        }
    }
    __syncthreads();
    for (int i = tid; i < len; i += 256) {
        unsigned int p = fit ? stage[i] : part[S + i];
        int dl = p >> 17;
        int s = (int)(p & 0x1FFFFu);
        int r = atomicAdd(&cur2[dl], 1);
        csr[S + excl[dl] + r] = s;
    }
}

// ---------------- W34 = W3 @ W4 (fp32), b34 = b3 @ W4 + b4 ----------------

__global__ __launch_bounds__(64) void w34_kernel(const float* __restrict__ W3,
                                                 const float* __restrict__ W4,
                                                 const float* __restrict__ b3,
                                                 const float* __restrict__ b4,
                                                 float* __restrict__ W34,
                                                 float* __restrict__ b34) {
    int j = threadIdx.x;
    int i = blockIdx.x;
    if (i < 64) {
        float a = 0.f;
        for (int k = 0; k < 256; ++k) a = fmaf(W3[i * 256 + k], W4[k * 64 + j], a);
        W34[i * 64 + j] = a;
    } else {
        float a = b4[j];
        for (int k = 0; k < 256; ++k) a = fmaf(b3[k], W4[k * 64 + j], a);
        b34[j] = a;
    }
}

// ---------------- pack W[K][64] fp32 -> bf16 B-fragment layout ----------------

template <int K>
__global__ __launch_bounds__(256) void packW_kernel(const float* __restrict__ W,
                                                    unsigned short* __restrict__ Wp) {
    constexpr int S = K / 32;
    int idx = blockIdx.x * 256 + threadIdx.x;
    if (idx >= 64 * K) return;
    int i = idx & 7;
    int rest = idx >> 3;
    int lane = rest & 63; rest >>= 6;
    int s = rest % S;
    int t = rest / S;
    int q = lane >> 4, lo = lane & 15;
    int k = s * 32 + q * 8 + i;
    int ch = t * 16 + lo;
    Wp[idx] = f2bf(W[k * 64 + ch]);
}

// ---------------- MFMA GEMM: out[N,64] = X[N,K] @ W[K,64] ----------------

template <int K, bool LSM, bool F32IN>
__global__ __launch_bounds__(256) void gemm_mfma_kernel(const unsigned short* __restrict__ Xb,
                                                        const float* __restrict__ Xf,
                                                        const unsigned short* __restrict__ Wp,
                                                        const float* __restrict__ bias,
                                                        const float* __restrict__ dinv,
                                                        unsigned short* __restrict__ outb,
                                                        float* __restrict__ outf, int n) {
    constexpr int S = K / 32;
    int w = threadIdx.x >> 6, lane = threadIdx.x & 63;
    int q = lane >> 4, lo = lane & 15;
    int base = blockIdx.x * 64 + w * 16;
    int nodeA = base + lo;
    int na = nodeA < n ? nodeA : 0;

    f32x4 acc[4] = {};
#pragma unroll
    for (int s = 0; s < S; ++s) {
        bf16x8 a;
        if (F32IN) {
            const float* xr = Xf + (size_t)na * K + q * 8 + s * 32;
            float4 u = *(const float4*)(xr);
            float4 v = *(const float4*)(xr + 4);
            a[0] = (__bf16)u.x; a[1] = (__bf16)u.y; a[2] = (__bf16)u.z; a[3] = (__bf16)u.w;
            a[4] = (__bf16)v.x; a[5] = (__bf16)v.y; a[6] = (__bf16)v.z; a[7] = (__bf16)v.w;
        } else {
            a = *(const bf16x8*)(Xb + (size_t)na * K + q * 8 + s * 32);
        }
#pragma unroll
        for (int t = 0; t < 4; ++t) {
            bf16x8 b = *(const bf16x8*)(Wp + ((size_t)(t * S + s) * 64 + lane) * 8);
            acc[t] = __builtin_amdgcn_mfma_f32_16x16x32_bf16(a, b, acc[t], 0, 0, 0);
        }
    }

    if (!LSM) {
#pragma unroll
        for (int r = 0; r < 4; ++r) {
            int node = base + q * 4 + r;
            if (node < n) {
                float di = dinv[node];
#pragma unroll
                for (int t = 0; t < 4; ++t)
                    outb[(size_t)node * 64 + t * 16 + lo] = f2bf(acc[t][r] * di);
            }
        }
    } else {
#pragma unroll
        for (int r = 0; r < 4; ++r) {
            int node = base + q * 4 + r;
            float v0 = acc[0][r] + bias[0 * 16 + lo];
            float v1 = acc[1][r] + bias[1 * 16 + lo];
            float v2 = acc[2][r] + bias[2 * 16 + lo];
            float v3 = acc[3][r] + bias[3 * 16 + lo];
            float mx = fmaxf(fmaxf(v0, v1), fmaxf(v2, v3));
            for (int d = 1; d < 16; d <<= 1) mx = fmaxf(mx, __shfl_xor(mx, d));
            float sm = __expf(v0 - mx) + __expf(v1 - mx) + __expf(v2 - mx) + __expf(v3 - mx);
            for (int d = 1; d < 16; d <<= 1) sm += __shfl_xor(sm, d);
            float lse = mx + __logf(sm);
            if (node < n) {
                outf[(size_t)node * 64 + 0 * 16 + lo] = v0 - lse;
                outf[(size_t)node * 64 + 1 * 16 + lo] = v1 - lse;
                outf[(size_t)node * 64 + 2 * 16 + lo] = v2 - lse;
                outf[(size_t)node * 64 + 3 * 16 + lo] = v3 - lse;
            }
        }
    }
}

// ---------------- aggregation: one wave per dst node ----------------
// 8 edges per gather instruction: lane l loads 16B (8 channels, base (l&7)*8)
// of edge i+(l>>3)'s row. Per-lane partial sums; 3-round shfl_xor (8/16/32)
// combines the 8 edge-groups at the end. Lanes 0-7 write the 128B output row.

__global__ __launch_bounds__(256) void aggregate_kernel(const unsigned short* __restrict__ hp,
                                                        const int* __restrict__ csr,
                                                        const int* __restrict__ off,
                                                        const int* __restrict__ cnt,
                                                        const float* __restrict__ dinv,
                                                        const float* __restrict__ bias,
                                                        unsigned short* __restrict__ out, int n) {
    int wid = (blockIdx.x * 256 + threadIdx.x) >> 6;
    int lane = threadIdx.x & 63;
    if (wid >= n) return;
    int g = lane >> 3;        // edge slot 0..7
    int c8 = (lane & 7) * 8;  // channel base

    float acc[8] = {};
    // self-loop: group 0 only (adds row wid exactly once across the wave)
    if (g == 0) {
        bf16x8 v = *(const bf16x8*)(hp + (size_t)wid * 64 + c8);
#pragma unroll
        for (int j = 0; j < 8; ++j) acc[j] += (float)v[j];
    }

    int s = off[wid];
    int e = s + cnt[wid];
    for (int i = s; i < e; i += 8) {
        int eidx = i + g;
        if (eidx < e) {
            int srcn = csr[eidx];
            bf16x8 v = *(const bf16x8*)(hp + (size_t)srcn * 64 + c8);
#pragma unroll
            for (int j = 0; j < 8; ++j) acc[j] += (float)v[j];
        }
    }

    // combine the 8 edge-groups (lanes stride-8 share a channel range)
#pragma unroll
    for (int d = 8; d < 64; d <<= 1)
#pragma unroll
        for (int j = 0; j < 8; ++j) acc[j] += __shfl_xor(acc[j], d);

    if (lane < 8) {
        float di = dinv[wid];
        float4 bv0 = *(const float4*)(bias + c8);
        float4 bv1 = *(const float4*)(bias + c8 + 4);
        float bb[8] = {bv0.x, bv0.y, bv0.z, bv0.w, bv1.x, bv1.y, bv1.z, bv1.w};
        ushort4 o0, o1;
        unsigned short ov[8];
#pragma unroll
        for (int j = 0; j < 8; ++j)
            ov[j] = f2bf(fmaxf(fmaf(acc[j], di, bb[j]), 0.f));
        o0 = make_ushort4(ov[0], ov[1], ov[2], ov[3]);
        o1 = make_ushort4(ov[4], ov[5], ov[6], ov[7]);
        *(ushort4*)(out + (size_t)wid * 64 + c8) = o0;
        *(ushort4*)(out + (size_t)wid * 64 + c8 + 4) = o1;
    }
}

// ---------------- launch ----------------

extern "C" void kernel_launch(void* const* d_in, const int* in_sizes, int n_in,
                              void* d_out, int out_size, void* d_ws, size_t ws_size,
                              hipStream_t stream) {
    const float* x  = (const float*)d_in[0];
    const int*   ei = (const int*)d_in[1];   // int32 (JAX x64 disabled demotes int64)
    const float* W1 = (const float*)d_in[2];
    const float* b1 = (const float*)d_in[3];
    const float* W2 = (const float*)d_in[4];
    const float* b2 = (const float*)d_in[5];
    const float* W3 = (const float*)d_in[6];
    const float* b3 = (const float*)d_in[7];
    const float* W4 = (const float*)d_in[8];
    const float* b4 = (const float*)d_in[9];
    float* outp = (float*)d_out;

    const int N = NNODES;
    const int E = NEDGES;
    const int* srcp = ei;
    const int* dstp = ei + E;

    char* w = (char*)d_ws;
    size_t o = 0;
    auto alloc = [&](size_t bytes) { size_t r = o; o = (o + bytes + 255) & ~(size_t)255; return r; };
    size_t cnt_off   = alloc((size_t)N * 4);
    size_t off_off   = alloc((size_t)N * 4);
    size_t dinv_off  = alloc((size_t)N * 4);
    size_t histg_off = alloc((size_t)SCAN_N * 4);
    size_t gscan_off = alloc((size_t)SCAN_N * 4);
    size_t gbT_off   = alloc((size_t)SCAN_N * 4);
    size_t bs_off    = alloc(256 * 4);
    size_t bse_off   = alloc(256 * 4);
    size_t part_off  = alloc((size_t)E * 4);
    size_t csr_off   = alloc((size_t)E * 4);
    size_t hp_off    = alloc((size_t)N * 64 * 2);
    size_t abf_off   = alloc((size_t)N * 64 * 2);
    size_t wp1_off   = alloc(128 * 64 * 2);
    size_t wp2_off   = alloc(64 * 64 * 2);
    size_t wp34_off  = alloc(64 * 64 * 2);
    size_t w34_off   = alloc(64 * 64 * 4);
    size_t b34_off   = alloc(64 * 4);

    int*            cnt   = (int*)(w + cnt_off);
    int*            off   = (int*)(w + off_off);
    float*          dinv  = (float*)(w + dinv_off);
    int*            histg = (int*)(w + histg_off);
    int*            gscan = (int*)(w + gscan_off);
    int*            gbT   = (int*)(w + gbT_off);
    int*            bs    = (int*)(w + bs_off);
    int*            bse   = (int*)(w + bse_off);
    unsigned int*   part  = (unsigned int*)(w + part_off);
    int*            csr   = (int*)(w + csr_off);
    unsigned short* hp    = (unsigned short*)(w + hp_off);
    unsigned short* abf   = (unsigned short*)(w + abf_off);
    unsigned short* Wp1   = (unsigned short*)(w + wp1_off);
    unsigned short* Wp2   = (unsigned short*)(w + wp2_off);
    unsigned short* Wp34  = (unsigned short*)(w + wp34_off);
    float*          W34f  = (float*)(w + w34_off);
    float*          b34   = (float*)(w + b34_off);

    const int sb = (SCAN_N + 1023) / 1024;   // 196
    const int s3b = (SCAN_N + 255) / 256;    // 783

    hist_kernel<<<PB, 256, 0, stream>>>(dstp, histg);
    scan1_kernel<<<sb, 256, 0, stream>>>(histg, gscan, bs, SCAN_N);
    scan2_kernel<<<1, 256, 0, stream>>>(bs, bse, sb);
    scan3t_kernel<<<s3b, 256, 0, stream>>>(gscan, bse, gbT, SCAN_N);
    part_kernel<<<PB, 256, 0, stream>>>(srcp, dstp, gbT, part);
    csr_kernel<<<NB, 256, 0, stream>>>(part, gbT, csr, cnt, off, dinv, N);

    w34_kernel<<<65, 64, 0, stream>>>(W3, W4, b3, b4, W34f, b34);
    packW_kernel<128><<<(128 * 64 + 255) / 256, 256, 0, stream>>>(W1, Wp1);
    packW_kernel<64><<<(64 * 64 + 255) / 256, 256, 0, stream>>>(W2, Wp2);
    packW_kernel<64><<<(64 * 64 + 255) / 256, 256, 0, stream>>>(W34f, Wp34);

    const int gb = (N + 63) / 64;       // 1563
    const int ab = (N + 3) / 4;         // 25000

    gemm_mfma_kernel<128, false, true><<<gb, 256, 0, stream>>>(nullptr, x, Wp1, nullptr, dinv, hp, nullptr, N);
    aggregate_kernel<<<ab, 256, 0, stream>>>(hp, csr, off, cnt, dinv, b1, abf, N);
    gemm_mfma_kernel<64, false, false><<<gb, 256, 0, stream>>>(abf, nullptr, Wp2, nullptr, dinv, hp, nullptr, N);
    aggregate_kernel<<<ab, 256, 0, stream>>>(hp, csr, off, cnt, dinv, b2, abf, N);
    gemm_mfma_kernel<64, true, false><<<gb, 256, 0, stream>>>(abf, nullptr, Wp34, b34, nullptr, nullptr, outp, N);
}

// Round 6
// 279.858 us; speedup vs baseline: 2.0778x; 1.1066x over previous
//
#include <hip/hip_runtime.h>
#include <hip/hip_bf16.h>
#include <math.h>

#define NNODES 100000
#define NEDGES 1600000
#define NB 782           // ceil(NNODES/128) buckets of 128 nodes
#define PB 256           // partition blocks
#define EPB 6250         // NEDGES / PB exactly
#define SCAN_N (NB * PB) // 200192
#define CAP 4608         // LDS stage capacity per bucket (avg 2048, max ~2300)

typedef __bf16 bf16x8 __attribute__((ext_vector_type(8)));
typedef float f32x4 __attribute__((ext_vector_type(4)));

static __device__ inline unsigned short f2bf(float f) {
    __hip_bfloat16 h = __float2bfloat16(f);
    return *reinterpret_cast<unsigned short*>(&h);
}

static __device__ inline float bf2f(unsigned short u) {
    unsigned int x = ((unsigned int)u) << 16;
    return __builtin_bit_cast(float, x);
}

// ---------------- pass A: per-block LDS histogram of dst>>7 ----------------

__global__ __launch_bounds__(256) void hist_kernel(const int* __restrict__ dst,
                                                   int* __restrict__ histg) {
    __shared__ int h[NB];
    int tid = threadIdx.x, blk = blockIdx.x;
    for (int b = tid; b < NB; b += 256) h[b] = 0;
    __syncthreads();
    int base = blk * EPB;
    for (int i = base + tid; i < base + EPB; i += 256)
        atomicAdd(&h[dst[i] >> 7], 1);
    __syncthreads();
    for (int b = tid; b < NB; b += 256) histg[b * PB + blk] = h[b];
}

// ---------------- scan chain over SCAN_N elements ----------------

__global__ __launch_bounds__(256) void scan1_kernel(const int* __restrict__ cnt,
                                                    int* __restrict__ off,
                                                    int* __restrict__ bsum, int n) {
    __shared__ int tmp[256];
    int tid = threadIdx.x;
    int t4 = blockIdx.x * 1024 + tid * 4;
    int v0 = (t4 + 0 < n) ? cnt[t4 + 0] : 0;
    int v1 = (t4 + 1 < n) ? cnt[t4 + 1] : 0;
    int v2 = (t4 + 2 < n) ? cnt[t4 + 2] : 0;
    int v3 = (t4 + 3 < n) ? cnt[t4 + 3] : 0;
    int ssum = v0 + v1 + v2 + v3;
    tmp[tid] = ssum;
    __syncthreads();
    for (int d = 1; d < 256; d <<= 1) {
        int x = (tid >= d) ? tmp[tid - d] : 0;
        __syncthreads();
        tmp[tid] += x;
        __syncthreads();
    }
    int run = tmp[tid] - ssum;
    if (t4 + 0 < n) off[t4 + 0] = run; run += v0;
    if (t4 + 1 < n) off[t4 + 1] = run; run += v1;
    if (t4 + 2 < n) off[t4 + 2] = run; run += v2;
    if (t4 + 3 < n) off[t4 + 3] = run;
    if (tid == 255) bsum[blockIdx.x] = tmp[255];
}

__global__ __launch_bounds__(256) void scan2_kernel(const int* __restrict__ bsum,
                                                    int* __restrict__ bsum_ex, int nb) {
    __shared__ int tmp[256];
    int tid = threadIdx.x;
    int v = (tid < nb) ? bsum[tid] : 0;
    tmp[tid] = v;
    __syncthreads();
    for (int d = 1; d < 256; d <<= 1) {
        int x = (tid >= d) ? tmp[tid - d] : 0;
        __syncthreads();
        tmp[tid] += x;
        __syncthreads();
    }
    bsum_ex[tid] = tmp[tid] - v;
}

__global__ __launch_bounds__(256) void scan3t_kernel(const int* __restrict__ part_scan,
                                                     const int* __restrict__ bsum_ex,
                                                     int* __restrict__ gbaseT, int n) {
    int i = blockIdx.x * 256 + threadIdx.x;
    if (i < n) {
        int v = part_scan[i] + bsum_ex[i >> 10];
        int b = i >> 8, blk = i & 255;
        gbaseT[blk * NB + b] = v;
    }
}

// ---------------- pass B: partition edges into bucket-ordered array ----------------

__global__ __launch_bounds__(256) void part_kernel(const int* __restrict__ src,
                                                   const int* __restrict__ dst,
                                                   const int* __restrict__ gbaseT,
                                                   unsigned int* __restrict__ part) {
    __shared__ int gcol[NB];
    __shared__ int cur[NB];
    int tid = threadIdx.x, blk = blockIdx.x;
    for (int b = tid; b < NB; b += 256) {
        gcol[b] = gbaseT[blk * NB + b];
        cur[b] = 0;
    }
    __syncthreads();
    int base = blk * EPB;
    for (int i = base + tid; i < base + EPB; i += 256) {
        int s = src[i], d = dst[i];
        int bkt = d >> 7;
        int r = atomicAdd(&cur[bkt], 1);
        part[gcol[bkt] + r] = ((unsigned int)(d & 127) << 17) | (unsigned int)s;
    }
}

// ---------------- pass C: per-bucket CSR build + cnt/off/dinv ----------------

__global__ __launch_bounds__(256) void csr_kernel(const unsigned int* __restrict__ part,
                                                  const int* __restrict__ gbaseT,
                                                  int* __restrict__ csr,
                                                  int* __restrict__ cnt_g,
                                                  int* __restrict__ off_g,
                                                  float* __restrict__ dinv_g, int n) {
    __shared__ unsigned int stage[CAP];
    __shared__ int hist2[128];
    __shared__ int sc[128];
    __shared__ int excl[128];
    __shared__ int cur2[128];
    int tid = threadIdx.x, b = blockIdx.x;
    int S = gbaseT[b];
    int T = (b == NB - 1) ? NEDGES : gbaseT[b + 1];
    int len = T - S;
    bool fit = (len <= CAP);
    if (tid < 128) { hist2[tid] = 0; cur2[tid] = 0; }
    __syncthreads();
    for (int i = tid; i < len; i += 256) {
        unsigned int p = part[S + i];
        if (fit) stage[i] = p;
        atomicAdd(&hist2[p >> 17], 1);
    }
    __syncthreads();
    if (tid < 128) sc[tid] = hist2[tid];
    __syncthreads();
    for (int d = 1; d < 128; d <<= 1) {
        int x = 0;
        if (tid < 128 && tid >= d) x = sc[tid - d];
        __syncthreads();
        if (tid < 128) sc[tid] += x;
        __syncthreads();
    }
    if (tid < 128) {
        int c = hist2[tid];
        int ex = sc[tid] - c;
        excl[tid] = ex;
        int node = b * 128 + tid;
        if (node < n) {
            cnt_g[node] = c;
            off_g[node] = S + ex;
            dinv_g[node] = rsqrtf((float)c + 1.0f);
        }
    }
    __syncthreads();
    for (int i = tid; i < len; i += 256) {
        unsigned int p = fit ? stage[i] : part[S + i];
        int dl = p >> 17;
        int s = (int)(p & 0x1FFFFu);
        int r = atomicAdd(&cur2[dl], 1);
        csr[S + excl[dl] + r] = s;
    }
}

// ---------------- W34 = W3 @ W4 (fp32), b34 = b3 @ W4 + b4 ----------------

__global__ __launch_bounds__(64) void w34_kernel(const float* __restrict__ W3,
                                                 const float* __restrict__ W4,
                                                 const float* __restrict__ b3,
                                                 const float* __restrict__ b4,
                                                 float* __restrict__ W34,
                                                 float* __restrict__ b34) {
    int j = threadIdx.x;
    int i = blockIdx.x;
    if (i < 64) {
        float a = 0.f;
        for (int k = 0; k < 256; ++k) a = fmaf(W3[i * 256 + k], W4[k * 64 + j], a);
        W34[i * 64 + j] = a;
    } else {
        float a = b4[j];
        for (int k = 0; k < 256; ++k) a = fmaf(b3[k], W4[k * 64 + j], a);
        b34[j] = a;
    }
}

// ---------------- pack W[K][64] fp32 -> bf16 B-fragment layout ----------------

template <int K>
__global__ __launch_bounds__(256) void packW_kernel(const float* __restrict__ W,
                                                    unsigned short* __restrict__ Wp) {
    constexpr int S = K / 32;
    int idx = blockIdx.x * 256 + threadIdx.x;
    if (idx >= 64 * K) return;
    int i = idx & 7;
    int rest = idx >> 3;
    int lane = rest & 63; rest >>= 6;
    int s = rest % S;
    int t = rest / S;
    int q = lane >> 4, lo = lane & 15;
    int k = s * 32 + q * 8 + i;
    int ch = t * 16 + lo;
    Wp[idx] = f2bf(W[k * 64 + ch]);
}

// ---------------- zero the pad row hp[N] (read by aggregate for oob slots) ----------------

__global__ __launch_bounds__(64) void zrow_kernel(unsigned short* __restrict__ hp) {
    hp[(size_t)NNODES * 64 + threadIdx.x] = 0;
}

// ---------------- MFMA GEMM: out[N,64] = X[N,K] @ W[K,64] ----------------

template <int K, bool LSM, bool F32IN>
__global__ __launch_bounds__(256) void gemm_mfma_kernel(const unsigned short* __restrict__ Xb,
                                                        const float* __restrict__ Xf,
                                                        const unsigned short* __restrict__ Wp,
                                                        const float* __restrict__ bias,
                                                        const float* __restrict__ dinv,
                                                        unsigned short* __restrict__ outb,
                                                        float* __restrict__ outf, int n) {
    constexpr int S = K / 32;
    int w = threadIdx.x >> 6, lane = threadIdx.x & 63;
    int q = lane >> 4, lo = lane & 15;
    int base = blockIdx.x * 64 + w * 16;
    int nodeA = base + lo;
    int na = nodeA < n ? nodeA : 0;

    f32x4 acc[4] = {};
#pragma unroll
    for (int s = 0; s < S; ++s) {
        bf16x8 a;
        if (F32IN) {
            const float* xr = Xf + (size_t)na * K + q * 8 + s * 32;
            float4 u = *(const float4*)(xr);
            float4 v = *(const float4*)(xr + 4);
            a[0] = (__bf16)u.x; a[1] = (__bf16)u.y; a[2] = (__bf16)u.z; a[3] = (__bf16)u.w;
            a[4] = (__bf16)v.x; a[5] = (__bf16)v.y; a[6] = (__bf16)v.z; a[7] = (__bf16)v.w;
        } else {
            a = *(const bf16x8*)(Xb + (size_t)na * K + q * 8 + s * 32);
        }
#pragma unroll
        for (int t = 0; t < 4; ++t) {
            bf16x8 b = *(const bf16x8*)(Wp + ((size_t)(t * S + s) * 64 + lane) * 8);
            acc[t] = __builtin_amdgcn_mfma_f32_16x16x32_bf16(a, b, acc[t], 0, 0, 0);
        }
    }

    if (!LSM) {
#pragma unroll
        for (int r = 0; r < 4; ++r) {
            int node = base + q * 4 + r;
            if (node < n) {
                float di = dinv[node];
#pragma unroll
                for (int t = 0; t < 4; ++t)
                    outb[(size_t)node * 64 + t * 16 + lo] = f2bf(acc[t][r] * di);
            }
        }
    } else {
#pragma unroll
        for (int r = 0; r < 4; ++r) {
            int node = base + q * 4 + r;
            float v0 = acc[0][r] + bias[0 * 16 + lo];
            float v1 = acc[1][r] + bias[1 * 16 + lo];
            float v2 = acc[2][r] + bias[2 * 16 + lo];
            float v3 = acc[3][r] + bias[3 * 16 + lo];
            float mx = fmaxf(fmaxf(v0, v1), fmaxf(v2, v3));
            for (int d = 1; d < 16; d <<= 1) mx = fmaxf(mx, __shfl_xor(mx, d));
            float sm = __expf(v0 - mx) + __expf(v1 - mx) + __expf(v2 - mx) + __expf(v3 - mx);
            for (int d = 1; d < 16; d <<= 1) sm += __shfl_xor(sm, d);
            float lse = mx + __logf(sm);
            if (node < n) {
                outf[(size_t)node * 64 + 0 * 16 + lo] = v0 - lse;
                outf[(size_t)node * 64 + 1 * 16 + lo] = v1 - lse;
                outf[(size_t)node * 64 + 2 * 16 + lo] = v2 - lse;
                outf[(size_t)node * 64 + 3 * 16 + lo] = v3 - lse;
            }
        }
    }
}

// ---------------- aggregation: one wave per dst node ----------------
// All <=64 neighbor indices preloaded in ONE coalesced load (lane l -> csr[s+l]);
// slot c holds wid (self-loop), remaining slots the zeroed pad row N. Per-iteration
// indices come from __shfl (no memory load in the chain); x2 unroll keeps two
// gathers in flight. 8 edges per gather instr: lane l covers 8 channels
// ((l&7)*8) of edge-slot (l>>3). 3-round shfl_xor combines groups at the end.

__global__ __launch_bounds__(256) void aggregate_kernel(const unsigned short* __restrict__ hp,
                                                        const int* __restrict__ csr,
                                                        const int* __restrict__ off,
                                                        const int* __restrict__ cnt,
                                                        const float* __restrict__ dinv,
                                                        const float* __restrict__ bias,
                                                        unsigned short* __restrict__ out, int n) {
    int wid = (blockIdx.x * 256 + threadIdx.x) >> 6;
    int lane = threadIdx.x & 63;
    if (wid >= n) return;
    int g = lane >> 3;        // edge slot 0..7
    int c8 = (lane & 7) * 8;  // channel base

    int s = off[wid];
    int c = cnt[wid];

    // preload indices: slots [0,c) = neighbors, slot c = self (if it fits), rest = pad
    int idx = n;
    if (lane < c) idx = csr[s + lane];
    else if (lane == c) idx = wid;   // only reachable when c <= 63

    int m = (c <= 63) ? c + 1 : 64;  // entries covered by the preload
    int steps = (m + 7) >> 3;

    float acc0[8] = {}, acc1[8] = {};
    int it = 0;
    for (; it + 2 <= steps; it += 2) {
        int sa = __shfl(idx, it * 8 + g);
        int sb = __shfl(idx, it * 8 + 8 + g);
        bf16x8 va = *(const bf16x8*)(hp + (size_t)sa * 64 + c8);
        bf16x8 vb = *(const bf16x8*)(hp + (size_t)sb * 64 + c8);
#pragma unroll
        for (int j = 0; j < 8; ++j) { acc0[j] += (float)va[j]; acc1[j] += (float)vb[j]; }
    }
    if (it < steps) {
        int sa = __shfl(idx, it * 8 + g);
        bf16x8 va = *(const bf16x8*)(hp + (size_t)sa * 64 + c8);
#pragma unroll
        for (int j = 0; j < 8; ++j) acc0[j] += (float)va[j];
    }

    if (c > 63) {  // rare tail: remaining edges + self-loop
        if (g == 0) {
            bf16x8 v = *(const bf16x8*)(hp + (size_t)wid * 64 + c8);
#pragma unroll
            for (int j = 0; j < 8; ++j) acc1[j] += (float)v[j];
        }
        for (int jj = 64 + g; jj < c; jj += 8) {
            int srcn = csr[s + jj];
            bf16x8 v = *(const bf16x8*)(hp + (size_t)srcn * 64 + c8);
#pragma unroll
            for (int j = 0; j < 8; ++j) acc0[j] += (float)v[j];
        }
    }

#pragma unroll
    for (int j = 0; j < 8; ++j) acc0[j] += acc1[j];

    // combine the 8 edge-groups (lanes stride-8 share a channel range)
#pragma unroll
    for (int d = 8; d < 64; d <<= 1)
#pragma unroll
        for (int j = 0; j < 8; ++j) acc0[j] += __shfl_xor(acc0[j], d);

    if (lane < 8) {
        float di = dinv[wid];
        float4 bv0 = *(const float4*)(bias + c8);
        float4 bv1 = *(const float4*)(bias + c8 + 4);
        float bb[8] = {bv0.x, bv0.y, bv0.z, bv0.w, bv1.x, bv1.y, bv1.z, bv1.w};
        unsigned short ov[8];
#pragma unroll
        for (int j = 0; j < 8; ++j)
            ov[j] = f2bf(fmaxf(fmaf(acc0[j], di, bb[j]), 0.f));
        *(ushort4*)(out + (size_t)wid * 64 + c8) = make_ushort4(ov[0], ov[1], ov[2], ov[3]);
        *(ushort4*)(out + (size_t)wid * 64 + c8 + 4) = make_ushort4(ov[4], ov[5], ov[6], ov[7]);
    }
}

// ---------------- launch ----------------

extern "C" void kernel_launch(void* const* d_in, const int* in_sizes, int n_in,
                              void* d_out, int out_size, void* d_ws, size_t ws_size,
                              hipStream_t stream) {
    const float* x  = (const float*)d_in[0];
    const int*   ei = (const int*)d_in[1];   // int32 (JAX x64 disabled demotes int64)
    const float* W1 = (const float*)d_in[2];
    const float* b1 = (const float*)d_in[3];
    const float* W2 = (const float*)d_in[4];
    const float* b2 = (const float*)d_in[5];
    const float* W3 = (const float*)d_in[6];
    const float* b3 = (const float*)d_in[7];
    const float* W4 = (const float*)d_in[8];
    const float* b4 = (const float*)d_in[9];
    float* outp = (float*)d_out;

    const int N = NNODES;
    const int E = NEDGES;
    const int* srcp = ei;
    const int* dstp = ei + E;

    char* w = (char*)d_ws;
    size_t o = 0;
    auto alloc = [&](size_t bytes) { size_t r = o; o = (o + bytes + 255) & ~(size_t)255; return r; };
    size_t cnt_off   = alloc((size_t)N * 4);
    size_t off_off   = alloc((size_t)N * 4);
    size_t dinv_off  = alloc((size_t)N * 4);
    size_t histg_off = alloc((size_t)SCAN_N * 4);
    size_t gscan_off = alloc((size_t)SCAN_N * 4);
    size_t gbT_off   = alloc((size_t)SCAN_N * 4);
    size_t bs_off    = alloc(256 * 4);
    size_t bse_off   = alloc(256 * 4);
    size_t part_off  = alloc((size_t)E * 4);
    size_t csr_off   = alloc((size_t)E * 4);
    size_t hp_off    = alloc((size_t)(N + 1) * 64 * 2);  // +1 zeroed pad row
    size_t abf_off   = alloc((size_t)N * 64 * 2);
    size_t wp1_off   = alloc(128 * 64 * 2);
    size_t wp2_off   = alloc(64 * 64 * 2);
    size_t wp34_off  = alloc(64 * 64 * 2);
    size_t w34_off   = alloc(64 * 64 * 4);
    size_t b34_off   = alloc(64 * 4);

    int*            cnt   = (int*)(w + cnt_off);
    int*            off   = (int*)(w + off_off);
    float*          dinv  = (float*)(w + dinv_off);
    int*            histg = (int*)(w + histg_off);
    int*            gscan = (int*)(w + gscan_off);
    int*            gbT   = (int*)(w + gbT_off);
    int*            bs    = (int*)(w + bs_off);
    int*            bse   = (int*)(w + bse_off);
    unsigned int*   part  = (unsigned int*)(w + part_off);
    int*            csr   = (int*)(w + csr_off);
    unsigned short* hp    = (unsigned short*)(w + hp_off);
    unsigned short* abf   = (unsigned short*)(w + abf_off);
    unsigned short* Wp1   = (unsigned short*)(w + wp1_off);
    unsigned short* Wp2   = (unsigned short*)(w + wp2_off);
    unsigned short* Wp34  = (unsigned short*)(w + wp34_off);
    float*          W34f  = (float*)(w + w34_off);
    float*          b34   = (float*)(w + b34_off);

    const int sb = (SCAN_N + 1023) / 1024;   // 196
    const int s3b = (SCAN_N + 255) / 256;    // 783

    hist_kernel<<<PB, 256, 0, stream>>>(dstp, histg);
    scan1_kernel<<<sb, 256, 0, stream>>>(histg, gscan, bs, SCAN_N);
    scan2_kernel<<<1, 256, 0, stream>>>(bs, bse, sb);
    scan3t_kernel<<<s3b, 256, 0, stream>>>(gscan, bse, gbT, SCAN_N);
    part_kernel<<<PB, 256, 0, stream>>>(srcp, dstp, gbT, part);
    csr_kernel<<<NB, 256, 0, stream>>>(part, gbT, csr, cnt, off, dinv, N);

    w34_kernel<<<65, 64, 0, stream>>>(W3, W4, b3, b4, W34f, b34);
    packW_kernel<128><<<(128 * 64 + 255) / 256, 256, 0, stream>>>(W1, Wp1);
    packW_kernel<64><<<(64 * 64 + 255) / 256, 256, 0, stream>>>(W2, Wp2);
    packW_kernel<64><<<(64 * 64 + 255) / 256, 256, 0, stream>>>(W34f, Wp34);
    zrow_kernel<<<1, 64, 0, stream>>>(hp);

    const int gb = (N + 63) / 64;       // 1563
    const int ab = (N + 3) / 4;         // 25000

    gemm_mfma_kernel<128, false, true><<<gb, 256, 0, stream>>>(nullptr, x, Wp1, nullptr, dinv, hp, nullptr, N);
    aggregate_kernel<<<ab, 256, 0, stream>>>(hp, csr, off, cnt, dinv, b1, abf, N);
    gemm_mfma_kernel<64, false, false><<<gb, 256, 0, stream>>>(abf, nullptr, Wp2, nullptr, dinv, hp, nullptr, N);
    aggregate_kernel<<<ab, 256, 0, stream>>>(hp, csr, off, cnt, dinv, b2, abf, N);
    gemm_mfma_kernel<64, true, false><<<gb, 256, 0, stream>>>(abf, nullptr, Wp34, b34, nullptr, nullptr, outp, N);
}